// Round 14
// baseline (4278.338 us; speedup 1.0000x reference)
//
#include <hip/hip_runtime.h>

// ---------------- problem constants ----------------
constexpr int kB  = 64;
constexpr int kS  = 512;
constexpr int kF  = 64;
constexpr int kH  = 512;
constexpr int kL  = 4;
constexpr int kDH = 64;
constexpr int kC   = 4;              // chunk length (4 steps per scan dispatch)
constexpr int kNC  = 128;            // chunks
constexpr int kSC  = 8;              // chunks per super-chunk
constexpr int kNSC = 16;             // super-chunks
constexpr int kHC  = 4;              // super-chunks per hyper-chunk
constexpr int kNHC = 4;              // hyper-chunks
#define EPS 1e-5f

typedef __attribute__((ext_vector_type(8))) short short8;
typedef __attribute__((ext_vector_type(4))) float f32x4;

// ---------------- bf16 helpers ----------------
__device__ __forceinline__ ushort f2b(float f){
  unsigned u; __builtin_memcpy(&u, &f, 4);
  unsigned r = (u + 0x7fffu + ((u >> 16) & 1u)) >> 16;  // RNE
  return (ushort)r;
}
__device__ __forceinline__ float b2f(ushort u){
  unsigned v = ((unsigned)u) << 16; float f; __builtin_memcpy(&f, &v, 4); return f;
}
__device__ __forceinline__ void unpack2(unsigned u, float& a, float& b){
  unsigned lo = u << 16, hi = u & 0xffff0000u;
  __builtin_memcpy(&a, &lo, 4); __builtin_memcpy(&b, &hi, 4);
}

// ---------------- prep: fp32 -> bf16 cast with scale ----------------
__global__ void cast_scale(const float* __restrict__ src, ushort* __restrict__ dst,
                           int n, float s){
  int i = blockIdx.x*256 + threadIdx.x;
  if (i < n) dst[i] = f2b(src[i]*s);
}

__global__ void zero_f32(float* __restrict__ p, int n){
  int i = blockIdx.x*256 + threadIdx.x;
  if (i < n) p[i] = 0.f;
}

// Afp[l][m][n] = (m==n ? 0.9 : 0) + float(bf16(0.1*Wh[l][n][m]))  -- row-major fp32
__global__ void prep_afp(const float* __restrict__ Wh, float* __restrict__ Afp){
  int i = blockIdx.x*256 + threadIdx.x;
  if (i >= kL*kH*kH) return;
  const int l = i >> 18, rem = i & 262143;
  const int m = rem >> 9, n = rem & 511;
  float v = b2f(f2b(0.1f * Wh[(size_t)l*kH*kH + (size_t)n*kH + m]));
  if (m == n) v += 0.9f;
  Afp[(size_t)l*kH*kH + (size_t)m*kH + n] = v;
}

// fp32 squaring GEMM, batched over 4 layers: Out[l] = In[l] @ In[l]
__global__ __launch_bounds__(512) void sqgemm(const float* __restrict__ In,
                                              float* __restrict__ Out){
  const int l = blockIdx.x >> 6;       // 4 layers
  const int rg = blockIdx.x & 63;      // row-group of 8
  const int j = threadIdx.x;
  const float* A = In + (size_t)l*kH*kH;
  float* C = Out + (size_t)l*kH*kH;
  __shared__ float ar[8][kH];
  #pragma unroll
  for (int r = 0; r < 8; ++r) ar[r][j] = A[(size_t)(rg*8 + r)*kH + j];
  __syncthreads();
  float acc[8] = {0,0,0,0,0,0,0,0};
  for (int k = 0; k < kH; ++k){
    const float bkj = A[(size_t)k*kH + j];
    #pragma unroll
    for (int r = 0; r < 8; ++r) acc[r] += ar[r][k] * bkj;
  }
  #pragma unroll
  for (int r = 0; r < 8; ++r) C[(size_t)(rg*8 + r)*kH + j] = acc[r];
}

// ---------------- MFMA GEMM: C[M,N](bf16) = A[M,K](bf16) @ W[N,K]^T + bias ----
// 64x64 output tile per wave: 4 A-frags x 4 W-frags -> 16 MFMA per K-iter.
__global__ __launch_bounds__(256) void gemm_bf16(
    const ushort* __restrict__ A, const ushort* __restrict__ W,
    ushort* __restrict__ C, int M, int N, int K,
    const float* __restrict__ pb1, const float* __restrict__ pb2, float bscale)
{
  const int wave = threadIdx.x >> 6, lane = threadIdx.x & 63;
  const int task = blockIdx.x*4 + wave;
  const int NT = N >> 6;
  const int mt = task / NT, ng = task % NT;
  const int r = lane & 15, quad = lane >> 4;

  const ushort* ap = A + (size_t)(mt*64 + r)*K + quad*8;
  const ushort* wp = W + (size_t)(ng*64 + r)*K + quad*8;
  f32x4 acc[4][4];
  #pragma unroll
  for (int t = 0; t < 4; ++t)
    #pragma unroll
    for (int j = 0; j < 4; ++j) acc[t][j] = (f32x4){0,0,0,0};

  #pragma unroll 2
  for (int k0 = 0; k0 < K; k0 += 32){
    short8 a0 = *(const short8*)(ap + k0);
    short8 a1 = *(const short8*)(ap + (size_t)16*K + k0);
    short8 a2 = *(const short8*)(ap + (size_t)32*K + k0);
    short8 a3 = *(const short8*)(ap + (size_t)48*K + k0);
    short8 b0 = *(const short8*)(wp + k0);
    short8 b1 = *(const short8*)(wp + (size_t)16*K + k0);
    short8 b2 = *(const short8*)(wp + (size_t)32*K + k0);
    short8 b3 = *(const short8*)(wp + (size_t)48*K + k0);
    acc[0][0] = __builtin_amdgcn_mfma_f32_16x16x32_bf16(a0, b0, acc[0][0], 0, 0, 0);
    acc[0][1] = __builtin_amdgcn_mfma_f32_16x16x32_bf16(a0, b1, acc[0][1], 0, 0, 0);
    acc[0][2] = __builtin_amdgcn_mfma_f32_16x16x32_bf16(a0, b2, acc[0][2], 0, 0, 0);
    acc[0][3] = __builtin_amdgcn_mfma_f32_16x16x32_bf16(a0, b3, acc[0][3], 0, 0, 0);
    acc[1][0] = __builtin_amdgcn_mfma_f32_16x16x32_bf16(a1, b0, acc[1][0], 0, 0, 0);
    acc[1][1] = __builtin_amdgcn_mfma_f32_16x16x32_bf16(a1, b1, acc[1][1], 0, 0, 0);
    acc[1][2] = __builtin_amdgcn_mfma_f32_16x16x32_bf16(a1, b2, acc[1][2], 0, 0, 0);
    acc[1][3] = __builtin_amdgcn_mfma_f32_16x16x32_bf16(a1, b3, acc[1][3], 0, 0, 0);
    acc[2][0] = __builtin_amdgcn_mfma_f32_16x16x32_bf16(a2, b0, acc[2][0], 0, 0, 0);
    acc[2][1] = __builtin_amdgcn_mfma_f32_16x16x32_bf16(a2, b1, acc[2][1], 0, 0, 0);
    acc[2][2] = __builtin_amdgcn_mfma_f32_16x16x32_bf16(a2, b2, acc[2][2], 0, 0, 0);
    acc[2][3] = __builtin_amdgcn_mfma_f32_16x16x32_bf16(a2, b3, acc[2][3], 0, 0, 0);
    acc[3][0] = __builtin_amdgcn_mfma_f32_16x16x32_bf16(a3, b0, acc[3][0], 0, 0, 0);
    acc[3][1] = __builtin_amdgcn_mfma_f32_16x16x32_bf16(a3, b1, acc[3][1], 0, 0, 0);
    acc[3][2] = __builtin_amdgcn_mfma_f32_16x16x32_bf16(a3, b2, acc[3][2], 0, 0, 0);
    acc[3][3] = __builtin_amdgcn_mfma_f32_16x16x32_bf16(a3, b3, acc[3][3], 0, 0, 0);
  }
  #pragma unroll
  for (int j = 0; j < 4; ++j){
    const int nn = ng*64 + j*16 + r;
    float bias = 0.f;
    if (pb1) bias += pb1[nn];
    if (pb2) bias += pb2[nn];
    bias *= bscale;
    #pragma unroll
    for (int t = 0; t < 4; ++t){
      #pragma unroll
      for (int i = 0; i < 4; ++i){
        const int mm = mt*64 + t*16 + quad*4 + i;
        C[(size_t)mm*N + nn] = f2b(acc[t][j][i] + bias);
      }
    }
  }
}

// ================= chunked scan, MFMA, 32 batches/block =================
// grid = 256 blocks = 128 chunks x 2 batch-groups of 32 batches; 8 waves/block.
// Per k-iter: 4 G loads feed 16 MFMAs (2 batch-tiles x 4 n-tiles x hi/lo).
template<bool FULL>
__global__ __launch_bounds__(512) void scan_mfma(
    const ushort* __restrict__ U,     // (B,S,H) bf16
    const ushort* __restrict__ G,     // (H,H) bf16 row-major [n][m] = bf16(0.1*Wh)
    const float* __restrict__ S,      // (B,NC,H) chunk-entry states (FULL only)
    float* __restrict__ Z,            // (B,NC,H) chunk-end states (!FULL only)
    ushort* __restrict__ nh)          // (B,S,H) bf16 (FULL only)
{
  const int c  = blockIdx.x & (kNC - 1);   // 0..127
  const int b0 = (blockIdx.x >> 7) * 32;   // 0 or 32
  const int wave = threadIdx.x >> 6, lane = threadIdx.x & 63;
  const int r = lane & 15, quad = lane >> 4;
  const int wbase = wave * 64;
  const int colq = quad * 4;

  __shared__ __align__(16) ushort hiL[2][32*kH];
  __shared__ __align__(16) ushort loL[2][32*kH];

  // swizzled byte offset into a [32][512] bf16 tile
  #define SWZ(row, bytecol) ((row)*1024 + ((bytecol) ^ (((row)&7) << 4)))

  const ushort* gp0 = G + (size_t)(wbase +  0 + r)*kH + quad*8;
  const ushort* gp1 = G + (size_t)(wbase + 16 + r)*kH + quad*8;
  const ushort* gp2 = G + (size_t)(wbase + 32 + r)*kH + quad*8;
  const ushort* gp3 = G + (size_t)(wbase + 48 + r)*kH + quad*8;

  float st[2][4][4];
  #pragma unroll
  for (int bt = 0; bt < 2; ++bt)
    #pragma unroll
    for (int t = 0; t < 4; ++t){
      if (FULL){
        const float4 s4 = *(const float4*)&S[((size_t)(b0 + bt*16 + r)*kNC + c)*kH
                                             + wbase + t*16 + colq];
        st[bt][t][0] = s4.x; st[bt][t][1] = s4.y;
        st[bt][t][2] = s4.z; st[bt][t][3] = s4.w;
      } else {
        st[bt][t][0] = st[bt][t][1] = st[bt][t][2] = st[bt][t][3] = 0.f;
      }
    }

  #pragma unroll
  for (int bt = 0; bt < 2; ++bt)
    #pragma unroll
    for (int t = 0; t < 4; ++t){
      ushort h[4], l[4];
      #pragma unroll
      for (int i = 0; i < 4; ++i){
        h[i] = f2b(st[bt][t][i]);
        l[i] = f2b(st[bt][t][i] - b2f(h[i]));
      }
      uint2 hw, lw;
      hw.x = (unsigned)h[0] | ((unsigned)h[1] << 16);
      hw.y = (unsigned)h[2] | ((unsigned)h[3] << 16);
      lw.x = (unsigned)l[0] | ((unsigned)l[1] << 16);
      lw.y = (unsigned)l[2] | ((unsigned)l[3] << 16);
      const int bc = (wbase + t*16 + colq) * 2;
      *(uint2*)((char*)hiL[0] + SWZ(bt*16 + r, bc)) = hw;
      *(uint2*)((char*)loL[0] + SWZ(bt*16 + r, bc)) = lw;
    }
  __syncthreads();

  const size_t ub0 = (size_t)(b0 +  0 + r)*kS*kH;
  const size_t ub1 = (size_t)(b0 + 16 + r)*kS*kH;
  int cur = 0;

  for (int jj = 0; jj < kC; ++jj){
    const int tt = c*kC + jj;

    uint2 uv[2][4];
    #pragma unroll
    for (int t = 0; t < 4; ++t){
      uv[0][t] = *(const uint2*)&U[ub0 + (size_t)tt*kH + wbase + t*16 + colq];
      uv[1][t] = *(const uint2*)&U[ub1 + (size_t)tt*kH + wbase + t*16 + colq];
    }

    const char* rdHi = (const char*)hiL[cur];
    const char* rdLo = (const char*)loL[cur];
    char* wrHi = (char*)hiL[cur ^ 1];
    char* wrLo = (char*)loL[cur ^ 1];

    f32x4 ah[2][4], al[2][4];
    #pragma unroll
    for (int bt = 0; bt < 2; ++bt)
      #pragma unroll
      for (int t = 0; t < 4; ++t){ ah[bt][t] = (f32x4){0,0,0,0}; al[bt][t] = (f32x4){0,0,0,0}; }

    __builtin_amdgcn_s_setprio(1);
    #pragma unroll 2
    for (int k0 = 0; k0 < kH; k0 += 32){
      const int rb = k0*2 + quad*16;   // 16B-aligned, swizzle-safe
      const short8 bh0 = *(const short8*)(rdHi + SWZ( 0 + r, rb));
      const short8 bl0 = *(const short8*)(rdLo + SWZ( 0 + r, rb));
      const short8 bh1 = *(const short8*)(rdHi + SWZ(16 + r, rb));
      const short8 bl1 = *(const short8*)(rdLo + SWZ(16 + r, rb));
      const short8 g0 = *(const short8*)(gp0 + k0);
      const short8 g1 = *(const short8*)(gp1 + k0);
      const short8 g2 = *(const short8*)(gp2 + k0);
      const short8 g3 = *(const short8*)(gp3 + k0);
      ah[0][0] = __builtin_amdgcn_mfma_f32_16x16x32_bf16(g0, bh0, ah[0][0], 0, 0, 0);
      ah[0][1] = __builtin_amdgcn_mfma_f32_16x16x32_bf16(g1, bh0, ah[0][1], 0, 0, 0);
      ah[0][2] = __builtin_amdgcn_mfma_f32_16x16x32_bf16(g2, bh0, ah[0][2], 0, 0, 0);
      ah[0][3] = __builtin_amdgcn_mfma_f32_16x16x32_bf16(g3, bh0, ah[0][3], 0, 0, 0);
      al[0][0] = __builtin_amdgcn_mfma_f32_16x16x32_bf16(g0, bl0, al[0][0], 0, 0, 0);
      al[0][1] = __builtin_amdgcn_mfma_f32_16x16x32_bf16(g1, bl0, al[0][1], 0, 0, 0);
      al[0][2] = __builtin_amdgcn_mfma_f32_16x16x32_bf16(g2, bl0, al[0][2], 0, 0, 0);
      al[0][3] = __builtin_amdgcn_mfma_f32_16x16x32_bf16(g3, bl0, al[0][3], 0, 0, 0);
      ah[1][0] = __builtin_amdgcn_mfma_f32_16x16x32_bf16(g0, bh1, ah[1][0], 0, 0, 0);
      ah[1][1] = __builtin_amdgcn_mfma_f32_16x16x32_bf16(g1, bh1, ah[1][1], 0, 0, 0);
      ah[1][2] = __builtin_amdgcn_mfma_f32_16x16x32_bf16(g2, bh1, ah[1][2], 0, 0, 0);
      ah[1][3] = __builtin_amdgcn_mfma_f32_16x16x32_bf16(g3, bh1, ah[1][3], 0, 0, 0);
      al[1][0] = __builtin_amdgcn_mfma_f32_16x16x32_bf16(g0, bl1, al[1][0], 0, 0, 0);
      al[1][1] = __builtin_amdgcn_mfma_f32_16x16x32_bf16(g1, bl1, al[1][1], 0, 0, 0);
      al[1][2] = __builtin_amdgcn_mfma_f32_16x16x32_bf16(g2, bl1, al[1][2], 0, 0, 0);
      al[1][3] = __builtin_amdgcn_mfma_f32_16x16x32_bf16(g3, bl1, al[1][3], 0, 0, 0);
    }
    __builtin_amdgcn_s_setprio(0);

    #pragma unroll
    for (int bt = 0; bt < 2; ++bt){
      const size_t ub = bt ? ub1 : ub0;
      #pragma unroll
      for (int t = 0; t < 4; ++t){
        const f32x4 acs = ah[bt][t] + al[bt][t];
        float u0, u1, u2, u3;
        unpack2(uv[bt][t].x, u0, u1); unpack2(uv[bt][t].y, u2, u3);
        const float n0 = 0.9f*st[bt][t][0] + u0 + acs[0];
        const float n1 = 0.9f*st[bt][t][1] + u1 + acs[1];
        const float n2 = 0.9f*st[bt][t][2] + u2 + acs[2];
        const float n3 = 0.9f*st[bt][t][3] + u3 + acs[3];
        st[bt][t][0] = n0; st[bt][t][1] = n1;
        st[bt][t][2] = n2; st[bt][t][3] = n3;
        const ushort h0 = f2b(n0), h1 = f2b(n1), h2 = f2b(n2), h3 = f2b(n3);
        const ushort l0 = f2b(n0 - b2f(h0)), l1 = f2b(n1 - b2f(h1));
        const ushort l2 = f2b(n2 - b2f(h2)), l3 = f2b(n3 - b2f(h3));
        uint2 hw, lw;
        hw.x = (unsigned)h0 | ((unsigned)h1 << 16);
        hw.y = (unsigned)h2 | ((unsigned)h3 << 16);
        lw.x = (unsigned)l0 | ((unsigned)l1 << 16);
        lw.y = (unsigned)l2 | ((unsigned)l3 << 16);
        const int bc = (wbase + t*16 + colq) * 2;
        *(uint2*)(wrHi + SWZ(bt*16 + r, bc)) = hw;
        *(uint2*)(wrLo + SWZ(bt*16 + r, bc)) = lw;
        if (FULL)
          *(uint2*)&nh[ub + (size_t)tt*kH + wbase + t*16 + colq] = hw;
      }
    }
    __syncthreads();   // single barrier: writes to cur^1 visible, reads of cur done
    cur ^= 1;
  }

  if (!FULL){
    #pragma unroll
    for (int bt = 0; bt < 2; ++bt)
      #pragma unroll
      for (int t = 0; t < 4; ++t){
        float4 z4; z4.x = st[bt][t][0]; z4.y = st[bt][t][1];
        z4.z = st[bt][t][2]; z4.w = st[bt][t][3];
        *(float4*)&Z[((size_t)(b0 + bt*16 + r)*kNC + c)*kH
                     + wbase + t*16 + colq] = z4;
      }
  }
  #undef SWZ
}

// ================= three-level boundary scan (fp32, coalesced) =================
// matvec: s'[n] = addend[n] + sum_m s[m]*A[m][n]; thread = output col n.

// (a) P8[b][cc] = zero-init state through chunks cc*kSC .. +kSC-1 (A^4 per chunk)
__global__ __launch_bounds__(512) void bscan_a(
    const float* __restrict__ A4, const float* __restrict__ Z,
    float* __restrict__ P8)
{
  const int b = blockIdx.x / kNSC, cc = blockIdx.x % kNSC;   // 1024 blocks
  const int n = threadIdx.x;
  __shared__ float s[kH];
  s[n] = Z[((size_t)b*kNC + cc*kSC)*kH + n];
  __syncthreads();
  for (int j = 1; j < kSC; ++j){
    float acc = Z[((size_t)b*kNC + cc*kSC + j)*kH + n];
    for (int m = 0; m < kH; m += 4){
      const float4 sv = *(const float4*)&s[m];
      acc += sv.x*A4[(size_t)m*kH + n]     + sv.y*A4[(size_t)(m+1)*kH + n]
           + sv.z*A4[(size_t)(m+2)*kH + n] + sv.w*A4[(size_t)(m+3)*kH + n];
    }
    __syncthreads();
    s[n] = acc;
    __syncthreads();
  }
  P8[((size_t)b*kNSC + cc)*kH + n] = s[n];
}

// (h1) Ph[b][hc] = zero-init state through super-chunks hc*kHC .. +kHC-1 (A^32)
__global__ __launch_bounds__(512) void bscan_h1(
    const float* __restrict__ A32, const float* __restrict__ P8,
    float* __restrict__ Ph)
{
  const int b = blockIdx.x / kNHC, hc = blockIdx.x % kNHC;   // 256 blocks
  const int n = threadIdx.x;
  __shared__ float s[kH];
  s[n] = P8[((size_t)b*kNSC + hc*kHC)*kH + n];
  __syncthreads();
  for (int j = 1; j < kHC; ++j){
    float acc = P8[((size_t)b*kNSC + hc*kHC + j)*kH + n];
    for (int m = 0; m < kH; m += 4){
      const float4 sv = *(const float4*)&s[m];
      acc += sv.x*A32[(size_t)m*kH + n]     + sv.y*A32[(size_t)(m+1)*kH + n]
           + sv.z*A32[(size_t)(m+2)*kH + n] + sv.w*A32[(size_t)(m+3)*kH + n];
    }
    __syncthreads();
    s[n] = acc;
    __syncthreads();
  }
  Ph[((size_t)b*kNHC + hc)*kH + n] = s[n];
}

// (h2) Sh[b][hc] = state entering hyper-chunk hc (A^128 recursion)
__global__ __launch_bounds__(512) void bscan_h2(
    const float* __restrict__ A128, const float* __restrict__ Ph,
    float* __restrict__ Sh)
{
  const int b = blockIdx.x, n = threadIdx.x;             // 64 blocks
  __shared__ float s[kH];
  Sh[((size_t)b*kNHC + 0)*kH + n] = 0.f;
  s[n] = Ph[((size_t)b*kNHC + 0)*kH + n];
  Sh[((size_t)b*kNHC + 1)*kH + n] = s[n];
  __syncthreads();
  for (int hc = 1; hc < kNHC - 1; ++hc){
    float acc = Ph[((size_t)b*kNHC + hc)*kH + n];
    for (int m = 0; m < kH; m += 4){
      const float4 sv = *(const float4*)&s[m];
      acc += sv.x*A128[(size_t)m*kH + n]     + sv.y*A128[(size_t)(m+1)*kH + n]
           + sv.z*A128[(size_t)(m+2)*kH + n] + sv.w*A128[(size_t)(m+3)*kH + n];
    }
    __syncthreads();
    s[n] = acc;
    Sh[((size_t)b*kNHC + hc + 1)*kH + n] = acc;
    __syncthreads();
  }
}

// (h3) S2[b][cc] = state entering super-chunk cc within each hyper-chunk (A^32)
__global__ __launch_bounds__(512) void bscan_h3(
    const float* __restrict__ A32, const float* __restrict__ P8,
    const float* __restrict__ Sh, float* __restrict__ S2)
{
  const int b = blockIdx.x / kNHC, hc = blockIdx.x % kNHC;   // 256 blocks
  const int n = threadIdx.x;
  __shared__ float s[kH];
  s[n] = Sh[((size_t)b*kNHC + hc)*kH + n];
  S2[((size_t)b*kNSC + hc*kHC)*kH + n] = s[n];
  __syncthreads();
  for (int j = 0; j < kHC - 1; ++j){
    float acc = P8[((size_t)b*kNSC + hc*kHC + j)*kH + n];
    for (int m = 0; m < kH; m += 4){
      const float4 sv = *(const float4*)&s[m];
      acc += sv.x*A32[(size_t)m*kH + n]     + sv.y*A32[(size_t)(m+1)*kH + n]
           + sv.z*A32[(size_t)(m+2)*kH + n] + sv.w*A32[(size_t)(m+3)*kH + n];
    }
    __syncthreads();
    s[n] = acc;
    S2[((size_t)b*kNSC + hc*kHC + j + 1)*kH + n] = acc;
    __syncthreads();
  }
}

// (c) emit all chunk-entry states within each super-chunk (A^4)
__global__ __launch_bounds__(512) void bscan_c(
    const float* __restrict__ A4, const float* __restrict__ Z,
    const float* __restrict__ S2, float* __restrict__ S)
{
  const int b = blockIdx.x / kNSC, cc = blockIdx.x % kNSC;   // 1024 blocks
  const int n = threadIdx.x;
  __shared__ float s[kH];
  s[n] = S2[((size_t)b*kNSC + cc)*kH + n];
  S[((size_t)b*kNC + cc*kSC)*kH + n] = s[n];
  __syncthreads();
  for (int j = 0; j < kSC - 1; ++j){
    float acc = Z[((size_t)b*kNC + cc*kSC + j)*kH + n];
    for (int m = 0; m < kH; m += 4){
      const float4 sv = *(const float4*)&s[m];
      acc += sv.x*A4[(size_t)m*kH + n]     + sv.y*A4[(size_t)(m+1)*kH + n]
           + sv.z*A4[(size_t)(m+2)*kH + n] + sv.w*A4[(size_t)(m+3)*kH + n];
    }
    __syncthreads();
    s[n] = acc;
    S[((size_t)b*kNC + cc*kSC + j + 1)*kH + n] = acc;
    __syncthreads();
  }
}

// ---------------- LayerNorm rows (in place on bf16) ----------------
__global__ __launch_bounds__(512) void ln_rows(
    ushort* __restrict__ act, const float* __restrict__ g, const float* __restrict__ bta)
{
  const size_t row = blockIdx.x;
  const int n = threadIdx.x, wid = n >> 6, lane = n & 63;
  __shared__ float red[16];
  const float y = b2f(act[row*kH + n]);
  float s1 = y, s2 = y*y;
  #pragma unroll
  for (int off = 32; off; off >>= 1){
    s1 += __shfl_down(s1, off); s2 += __shfl_down(s2, off);
  }
  if (lane == 0){ red[wid] = s1; red[8 + wid] = s2; }
  __syncthreads();
  float m = 0.f, q = 0.f;
  #pragma unroll
  for (int i = 0; i < 8; ++i){ m += red[i]; q += red[8+i]; }
  m *= (1.f/kH); q *= (1.f/kH);
  const float var = q - m*m;
  const float hv = (y - m) * rsqrtf(var + EPS) * g[n] + bta[n];
  act[row*kH + n] = f2b(hv);
}

// ---------------- seqmean (fp32) from bf16 act ----------------
__global__ __launch_bounds__(512) void seqmean_k(
    const ushort* __restrict__ act, float* __restrict__ seqmean)
{
  const int b = blockIdx.x, n = threadIdx.x;
  float acc = 0.f;
  for (int t = 0; t < kS; ++t) acc += b2f(act[((size_t)b*kS + t)*kH + n]);
  seqmean[(size_t)b*kH + n] = acc * (1.f/kS);
}

// ---------------- MFMA flash attention on precomputed qkv (bf16) -------------
__global__ __launch_bounds__(512) void attn_chunk(
    const ushort* __restrict__ qkv,   // (16*S, 3H) bf16
    float* __restrict__ aomean, int b0)
{
  const int bb = blockIdx.x >> 5;          // batch within chunk
  const int h  = (blockIdx.x >> 2) & 7;    // head
  const int qt = blockIdx.x & 3;           // 128-query tile
  const int tid = threadIdx.x, wave = tid >> 6, lane = tid & 63;
  const int r = lane & 15, quad = lane >> 4;

  __shared__ __align__(16) ushort kt[64][72];      // [key][dim]
  __shared__ __align__(16) ushort vt[64][72];      // transposed: [dim][key]
  __shared__ ushort pt[8][16][72];                 // per-wave P [q_local][key]
  __shared__ float aom[kDH];
  if (tid < kDH) aom[tid] = 0.f;

  const int q0 = qt*128 + wave*16;
  short8 qa0, qa1;
  {
    const ushort* qp = qkv + ((size_t)bb*kS + q0 + r)*(3*kH) + h*kDH + quad*8;
    qa0 = *(const short8*)qp;
    qa1 = *(const short8*)(qp + 32);
  }

  f32x4 oc0={0,0,0,0}, oc1={0,0,0,0}, oc2={0,0,0,0}, oc3={0,0,0,0};
  float mRow[4] = {-1e30f,-1e30f,-1e30f,-1e30f};
  float lRow[4] = {0.f,0.f,0.f,0.f};

  const int srow = tid & 63;
  const int sd0  = (tid >> 6) * 8;

  for (int kt0 = 0; kt0 < kS/64; ++kt0){
    {
      const size_t rbase = ((size_t)bb*kS + kt0*64 + srow)*(3*kH) + h*kDH + sd0;
      *(uint4*)&kt[srow][sd0] = *(const uint4*)(qkv + rbase + kH);
      uint4 v4 = *(const uint4*)(qkv + rbase + 2*kH);
      const ushort* vs = (const ushort*)&v4;
      #pragma unroll
      for (int ii = 0; ii < 8; ++ii) vt[sd0 + ii][srow] = vs[ii];
    }
    __syncthreads();

    f32x4 ac0={0,0,0,0}, ac1={0,0,0,0}, ac2={0,0,0,0}, ac3={0,0,0,0};
    #pragma unroll
    for (int k0 = 0; k0 < 2; ++k0){
      const short8 av = k0 ? qa1 : qa0;
      const short8 b0v = *(const short8*)&kt[ 0 + r][k0*32 + quad*8];
      const short8 b1v = *(const short8*)&kt[16 + r][k0*32 + quad*8];
      const short8 b2v = *(const short8*)&kt[32 + r][k0*32 + quad*8];
      const short8 b3v = *(const short8*)&kt[48 + r][k0*32 + quad*8];
      ac0 = __builtin_amdgcn_mfma_f32_16x16x32_bf16(av, b0v, ac0, 0, 0, 0);
      ac1 = __builtin_amdgcn_mfma_f32_16x16x32_bf16(av, b1v, ac1, 0, 0, 0);
      ac2 = __builtin_amdgcn_mfma_f32_16x16x32_bf16(av, b2v, ac2, 0, 0, 0);
      ac3 = __builtin_amdgcn_mfma_f32_16x16x32_bf16(av, b3v, ac3, 0, 0, 0);
    }
    const f32x4 sc0 = ac0 * 0.125f, sc1 = ac1 * 0.125f,
                sc2 = ac2 * 0.125f, sc3 = ac3 * 0.125f;

    float p0[4], p1[4], p2[4], p3[4];
    #pragma unroll
    for (int i = 0; i < 4; ++i){
      float mx = fmaxf(fmaxf(sc0[i], sc1[i]), fmaxf(sc2[i], sc3[i]));
      #pragma unroll
      for (int off = 1; off < 16; off <<= 1) mx = fmaxf(mx, __shfl_xor(mx, off));
      const float nm = fmaxf(mRow[i], mx);
      const float corr = __expf(mRow[i] - nm);
      mRow[i] = nm;
      p0[i] = __expf(sc0[i] - nm); p1[i] = __expf(sc1[i] - nm);
      p2[i] = __expf(sc2[i] - nm); p3[i] = __expf(sc3[i] - nm);
      float rs = p0[i] + p1[i] + p2[i] + p3[i];
      #pragma unroll
      for (int off = 1; off < 16; off <<= 1) rs += __shfl_xor(rs, off);
      lRow[i] = lRow[i]*corr + rs;
      oc0[i] *= corr; oc1[i] *= corr; oc2[i] *= corr; oc3[i] *= corr;
    }

    #pragma unroll
    for (int i = 0; i < 4; ++i){
      pt[wave][quad*4 + i][ 0 + r] = f2b(p0[i]);
      pt[wave][quad*4 + i][16 + r] = f2b(p1[i]);
      pt[wave][quad*4 + i][32 + r] = f2b(p2[i]);
      pt[wave][quad*4 + i][48 + r] = f2b(p3[i]);
    }

    #pragma unroll
    for (int k0 = 0; k0 < 2; ++k0){
      const short8 pa  = *(const short8*)&pt[wave][r][k0*32 + quad*8];
      const short8 v0v = *(const short8*)&vt[ 0 + r][k0*32 + quad*8];
      const short8 v1v = *(const short8*)&vt[16 + r][k0*32 + quad*8];
      const short8 v2v = *(const short8*)&vt[32 + r][k0*32 + quad*8];
      const short8 v3v = *(const short8*)&vt[48 + r][k0*32 + quad*8];
      oc0 = __builtin_amdgcn_mfma_f32_16x16x32_bf16(pa, v0v, oc0, 0, 0, 0);
      oc1 = __builtin_amdgcn_mfma_f32_16x16x32_bf16(pa, v1v, oc1, 0, 0, 0);
      oc2 = __builtin_amdgcn_mfma_f32_16x16x32_bf16(pa, v2v, oc2, 0, 0, 0);
      oc3 = __builtin_amdgcn_mfma_f32_16x16x32_bf16(pa, v3v, oc3, 0, 0, 0);
    }
    __syncthreads();
  }

  float inv[4];
  #pragma unroll
  for (int i = 0; i < 4; ++i) inv[i] = 1.f / lRow[i];
  {
    float v;
    v = oc0[0]*inv[0] + oc0[1]*inv[1] + oc0[2]*inv[2] + oc0[3]*inv[3];
    v += __shfl_xor(v, 16); v += __shfl_xor(v, 32);
    if (quad == 0) atomicAdd(&aom[ 0 + r], v);
    v = oc1[0]*inv[0] + oc1[1]*inv[1] + oc1[2]*inv[2] + oc1[3]*inv[3];
    v += __shfl_xor(v, 16); v += __shfl_xor(v, 32);
    if (quad == 0) atomicAdd(&aom[16 + r], v);
    v = oc2[0]*inv[0] + oc2[1]*inv[1] + oc2[2]*inv[2] + oc2[3]*inv[3];
    v += __shfl_xor(v, 16); v += __shfl_xor(v, 32);
    if (quad == 0) atomicAdd(&aom[32 + r], v);
    v = oc3[0]*inv[0] + oc3[1]*inv[1] + oc3[2]*inv[2] + oc3[3]*inv[3];
    v += __shfl_xor(v, 16); v += __shfl_xor(v, 32);
    if (quad == 0) atomicAdd(&aom[48 + r], v);
  }
  __syncthreads();
  if (tid < kDH)
    atomicAdd(&aomean[(size_t)(b0 + bb)*kH + h*kDH + tid], aom[tid] * (1.f/kS));
}

// ---- pooled = seqmean + aomean@out_w^T + out_b (fp32) ----
__global__ __launch_bounds__(512) void pooled_kernel(
    const float* __restrict__ seqmean, const float* __restrict__ aomean,
    const float* __restrict__ outw, const float* __restrict__ outb,
    float* __restrict__ pooled)
{
  const int b = blockIdx.x, n = threadIdx.x;
  __shared__ float a[kH];
  a[n] = aomean[(size_t)b*kH + n];
  __syncthreads();
  const float* w = outw + (size_t)n*kH;
  float acc = outb[n];
  for (int m = 0; m < kH; ++m) acc += w[m] * a[m];
  pooled[(size_t)b*kH + n] = seqmean[(size_t)b*kH + n] + acc;
}

// ---------------- heads (fp32, validated) ----------------
__global__ __launch_bounds__(256) void heads_kernel(
    const float* __restrict__ pooled,
    const float* Wd1, const float* bd1, const float* Wd2, const float* bd2,
    const float* Wd3, const float* bd3,
    const float* Wq1, const float* bq1, const float* Wq2, const float* bq2,
    const float* Wq3, const float* bq3,
    const float* Wc1, const float* bc1, const float* Wc2, const float* bc2,
    float* __restrict__ out)
{
  const int b = blockIdx.x, tid = threadIdx.x;
  __shared__ float p[kH];
  __shared__ float a1d[256], a1q[256], a1c[256];
  __shared__ float a2d[128], a2q[128];
  p[tid]       = pooled[(size_t)b*kH + tid];
  p[tid + 256] = pooled[(size_t)b*kH + tid + 256];
  __syncthreads();
  {
    const float *w1 = Wd1 + (size_t)tid*kH, *w2 = Wq1 + (size_t)tid*kH,
                *w3 = Wc1 + (size_t)tid*kH;
    float v1 = bd1[tid], v2 = bq1[tid], v3 = bc1[tid];
    for (int m = 0; m < kH; ++m){
      v1 += w1[m]*p[m]; v2 += w2[m]*p[m]; v3 += w3[m]*p[m];
    }
    a1d[tid] = fmaxf(v1, 0.f); a1q[tid] = fmaxf(v2, 0.f); a1c[tid] = fmaxf(v3, 0.f);
  }
  __syncthreads();
  if (tid < 128){
    const float *w1 = Wd2 + (size_t)tid*256, *w2 = Wq2 + (size_t)tid*256;
    float v1 = bd2[tid], v2 = bq2[tid];
    for (int m = 0; m < 256; ++m){ v1 += w1[m]*a1d[m]; v2 += w2[m]*a1q[m]; }
    a2d[tid] = fmaxf(v1, 0.f); a2q[tid] = fmaxf(v2, 0.f);
  }
  __syncthreads();
  if (tid == 0){
    float d0 = bd3[0], d1 = bd3[1], pr = bq3[0], c = bc2[0];
    for (int m = 0; m < 128; ++m){
      d0 += Wd3[m]*a2d[m]; d1 += Wd3[128+m]*a2d[m]; pr += Wq3[m]*a2q[m];
    }
    for (int m = 0; m < 256; ++m) c += Wc2[m]*a1c[m];
    c = 1.f / (1.f + __expf(-c));
    out[2*b + 0]  = d0;
    out[2*b + 1]  = d1;
    out[2*kB + b] = pr;
    out[3*kB + b] = c;
  }
}

// ---------------- launch ----------------
extern "C" void kernel_launch(void* const* d_in, const int* in_sizes, int n_in,
                              void* d_out, int out_size, void* d_ws, size_t ws_size,
                              hipStream_t stream) {
  const float* x    = (const float*)d_in[0];
  const float* Win0 = (const float*)d_in[1];
  const float* bin0 = (const float*)d_in[2];
  const float* Wi   = (const float*)d_in[3];
  const float* bi   = (const float*)d_in[4];
  const float* Wh   = (const float*)d_in[5];
  const float* bh   = (const float*)d_in[6];
  const float* Wo   = (const float*)d_in[7];
  const float* bo   = (const float*)d_in[8];
  const float* lng  = (const float*)d_in[9];
  const float* lnb  = (const float*)d_in[10];
  const float* ipw  = (const float*)d_in[11];
  const float* ipb  = (const float*)d_in[12];
  const float* outw = (const float*)d_in[13];
  const float* outb = (const float*)d_in[14];

  char* wsb = (char*)d_ws;
  const size_t MB = 1u << 20;
  ushort* act   = (ushort*)(wsb);               // 32 MiB
  ushort* U     = (ushort*)(wsb + 32*MB);       // 32 MiB (reused as qkv)
  ushort* nh    = (ushort*)(wsb + 64*MB);       // 32 MiB
  ushort* wh_bf = (ushort*)(wsb + 96*MB);       // 2 MiB (0.1-scaled Wh, [n][m])
  ushort* wi_bf = (ushort*)(wsb + 98*MB);       // 2 MiB (0.1-scaled)
  ushort* wo_bf = (ushort*)(wsb + 100*MB);      // 2 MiB
  float*  Afp   = (float*)(wsb + 102*MB);       // 4 MiB (ends A^4)
  float*  Afp2  = (float*)(wsb + 106*MB);       // 4 MiB (ends A^32)
  float*  A128b = (float*)(wsb + 110*MB);       // 4 MiB (A^128)
  ushort* w0_bf = (ushort*)(wsb + 114*MB);      // 64 KiB
  ushort* ip_bf = (ushort*)(wsb + 114*MB + 65536);            // 1.5 MiB
  ushort* x_bf  = (ushort*)(wsb + 114*MB + 65536 + 1572864);  // 4 MiB
  float*  Apow  = (float*)x_bf;                 // power temp (after input gemm)
  // act dead-window overlays (between Wi-gemm read and Wo-gemm write):
  float*  Zb    = (float*)act;                  // 16 MiB (B*NC*H fp32, NC=128)
  float*  S     = (float*)(wsb + 16*MB);        // 16 MiB (chunk-entry states)
  // nh dead-window overlays (pre-FULL):
  float*  P8    = (float*)nh;                   // 2 MiB
  float*  S2    = (float*)(wsb + 66*MB);        // 2 MiB
  float*  Ph    = (float*)(wsb + 68*MB);        // 512 KiB
  float*  Sh    = (float*)(wsb + 69*MB);        // 512 KiB
  char*   tail  = wsb + 114*MB + 65536 + 1572864 + 4194304;
  float* seqmean = (float*)tail;
  float* aomean  = seqmean + (size_t)kB*kH;
  float* pooled  = aomean  + (size_t)kB*kH;
  ushort* qkv    = U;   // overlay: U dead after scan phase

  // ---- prep casts ----
  cast_scale<<<(kB*kS*kF + 255)/256, 256, 0, stream>>>(x, x_bf, kB*kS*kF, 1.f);
  cast_scale<<<(kH*kF + 255)/256, 256, 0, stream>>>(Win0, w0_bf, kH*kF, 1.f);
  cast_scale<<<(kL*kH*kH + 255)/256, 256, 0, stream>>>(Wi, wi_bf, kL*kH*kH, 0.1f);
  cast_scale<<<(kL*kH*kH + 255)/256, 256, 0, stream>>>(Wo, wo_bf, kL*kH*kH, 1.f);
  cast_scale<<<(kL*kH*kH + 255)/256, 256, 0, stream>>>(Wh, wh_bf, kL*kH*kH, 0.1f);
  cast_scale<<<(3*kH*kH + 255)/256, 256, 0, stream>>>(ipw, ip_bf, 3*kH*kH, 1.f);
  prep_afp<<<(kL*kH*kH + 255)/256, 256, 0, stream>>>(Wh, Afp);
  // A^4 (ends in Afp)
  sqgemm<<<kL*64, 512, 0, stream>>>(Afp,  Afp2);   // A^2
  sqgemm<<<kL*64, 512, 0, stream>>>(Afp2, Afp);    // A^4  (keep)

  constexpr int M = kB*kS;   // 32768
  // input gemm consumes x_bf BEFORE Apow reuses its region
  gemm_bf16<<<(M/64)*(kH/64)/4, 256, 0, stream>>>(x_bf, w0_bf, act, M, kH, kF,
                                                  bin0, nullptr, 1.f);
  // A^32 (Afp2) and A^128 (A128b); temps use Afp2/x_bf
  sqgemm<<<kL*64, 512, 0, stream>>>(Afp,  Afp2);   // A^8
  sqgemm<<<kL*64, 512, 0, stream>>>(Afp2, Apow);   // A^16
  sqgemm<<<kL*64, 512, 0, stream>>>(Apow, Afp2);   // A^32 (keep)
  sqgemm<<<kL*64, 512, 0, stream>>>(Afp2, Apow);   // A^64
  sqgemm<<<kL*64, 512, 0, stream>>>(Apow, A128b);  // A^128 (keep)

  for (int l = 0; l < kL; ++l){
    gemm_bf16<<<(M/64)*(kH/64)/4, 256, 0, stream>>>(
        act, wi_bf + (size_t)l*kH*kH, U, M, kH, kH,
        bi + (size_t)l*kH, bh + (size_t)l*kH, 0.1f);
    scan_mfma<false><<<2*kNC, 512, 0, stream>>>(U, wh_bf + (size_t)l*kH*kH,
                                                nullptr, Zb, nullptr);
    bscan_a<<<kB*kNSC, 512, 0, stream>>>(Afp + (size_t)l*kH*kH, Zb, P8);
    bscan_h1<<<kB*kNHC, 512, 0, stream>>>(Afp2 + (size_t)l*kH*kH, P8, Ph);
    bscan_h2<<<kB, 512, 0, stream>>>(A128b + (size_t)l*kH*kH, Ph, Sh);
    bscan_h3<<<kB*kNHC, 512, 0, stream>>>(Afp2 + (size_t)l*kH*kH, P8, Sh, S2);
    bscan_c<<<kB*kNSC, 512, 0, stream>>>(Afp + (size_t)l*kH*kH, Zb, S2, S);
    scan_mfma<true><<<2*kNC, 512, 0, stream>>>(U, wh_bf + (size_t)l*kH*kH,
                                               S, nullptr, nh);
    gemm_bf16<<<(M/64)*(kH/64)/4, 256, 0, stream>>>(
        nh, wo_bf + (size_t)l*kH*kH, act, M, kH, kH,
        bo + (size_t)l*kH, nullptr, 1.f);
    ln_rows<<<M, kH, 0, stream>>>(act, lng + (size_t)l*kH, lnb + (size_t)l*kH);
  }

  seqmean_k<<<kB, kH, 0, stream>>>(act, seqmean);

  zero_f32<<<(kB*kH + 255)/256, 256, 0, stream>>>(aomean, kB*kH);
  for (int c = 0; c < 4; ++c){
    const int Mc = 16*kS;   // 8192
    gemm_bf16<<<(Mc/64)*(3*kH/64)/4, 256, 0, stream>>>(
        act + (size_t)c*Mc*kH, ip_bf, qkv, Mc, 3*kH, kH, ipb, nullptr, 1.f);
    attn_chunk<<<512, 512, 0, stream>>>(qkv, aomean, c*16);
  }

  pooled_kernel<<<kB, kH, 0, stream>>>(seqmean, aomean, outw, outb, pooled);

  heads_kernel<<<kB, 256, 0, stream>>>(pooled,
      (const float*)d_in[15], (const float*)d_in[16], (const float*)d_in[17],
      (const float*)d_in[18], (const float*)d_in[19], (const float*)d_in[20],
      (const float*)d_in[21], (const float*)d_in[22], (const float*)d_in[23],
      (const float*)d_in[24], (const float*)d_in[25], (const float*)d_in[26],
      (const float*)d_in[27], (const float*)d_in[28], (const float*)d_in[29],
      (const float*)d_in[30], (float*)d_out);
}

// Round 15
// 4027.150 us; speedup vs baseline: 1.0624x; 1.0624x over previous
//
#include <hip/hip_runtime.h>

// ---------------- problem constants ----------------
constexpr int kB  = 64;
constexpr int kS  = 512;
constexpr int kF  = 64;
constexpr int kH  = 512;
constexpr int kL  = 4;
constexpr int kDH = 64;
constexpr int kC   = 4;              // chunk length (4 steps per scan dispatch)
constexpr int kNC  = 128;            // chunks
constexpr int kSC  = 8;              // chunks per super-chunk
constexpr int kNSC = 16;             // super-chunks
constexpr int kHC  = 4;              // super-chunks per hyper-chunk
constexpr int kNHC = 4;              // hyper-chunks
#define EPS 1e-5f

typedef __attribute__((ext_vector_type(8))) short short8;
typedef __attribute__((ext_vector_type(4))) float f32x4;

// ---------------- bf16 helpers ----------------
__device__ __forceinline__ ushort f2b(float f){
  unsigned u; __builtin_memcpy(&u, &f, 4);
  unsigned r = (u + 0x7fffu + ((u >> 16) & 1u)) >> 16;  // RNE
  return (ushort)r;
}
__device__ __forceinline__ float b2f(ushort u){
  unsigned v = ((unsigned)u) << 16; float f; __builtin_memcpy(&f, &v, 4); return f;
}
__device__ __forceinline__ void unpack2(unsigned u, float& a, float& b){
  unsigned lo = u << 16, hi = u & 0xffff0000u;
  __builtin_memcpy(&a, &lo, 4); __builtin_memcpy(&b, &hi, 4);
}

// ---------------- prep: fp32 -> bf16 cast with scale ----------------
__global__ void cast_scale(const float* __restrict__ src, ushort* __restrict__ dst,
                           int n, float s){
  int i = blockIdx.x*256 + threadIdx.x;
  if (i < n) dst[i] = f2b(src[i]*s);
}

__global__ void zero_f32(float* __restrict__ p, int n){
  int i = blockIdx.x*256 + threadIdx.x;
  if (i < n) p[i] = 0.f;
}

// Afp[l][m][n] = (m==n ? 0.9 : 0) + float(bf16(0.1*Wh[l][n][m]))  -- row-major fp32
__global__ void prep_afp(const float* __restrict__ Wh, float* __restrict__ Afp){
  int i = blockIdx.x*256 + threadIdx.x;
  if (i >= kL*kH*kH) return;
  const int l = i >> 18, rem = i & 262143;
  const int m = rem >> 9, n = rem & 511;
  float v = b2f(f2b(0.1f * Wh[(size_t)l*kH*kH + (size_t)n*kH + m]));
  if (m == n) v += 0.9f;
  Afp[(size_t)l*kH*kH + (size_t)m*kH + n] = v;
}

// fp32 squaring GEMM, batched over 4 layers: Out[l] = In[l] @ In[l]
__global__ __launch_bounds__(512) void sqgemm(const float* __restrict__ In,
                                              float* __restrict__ Out){
  const int l = blockIdx.x >> 6;       // 4 layers
  const int rg = blockIdx.x & 63;      // row-group of 8
  const int j = threadIdx.x;
  const float* A = In + (size_t)l*kH*kH;
  float* C = Out + (size_t)l*kH*kH;
  __shared__ float ar[8][kH];
  #pragma unroll
  for (int r = 0; r < 8; ++r) ar[r][j] = A[(size_t)(rg*8 + r)*kH + j];
  __syncthreads();
  float acc[8] = {0,0,0,0,0,0,0,0};
  for (int k = 0; k < kH; ++k){
    const float bkj = A[(size_t)k*kH + j];
    #pragma unroll
    for (int r = 0; r < 8; ++r) acc[r] += ar[r][k] * bkj;
  }
  #pragma unroll
  for (int r = 0; r < 8; ++r) C[(size_t)(rg*8 + r)*kH + j] = acc[r];
}

// ---------------- MFMA GEMM: C[M,N](bf16) = A[M,K](bf16) @ W[N,K]^T + bias ----
// 64x64 output tile per wave: 4 A-frags x 4 W-frags -> 16 MFMA per K-iter.
__global__ __launch_bounds__(256) void gemm_bf16(
    const ushort* __restrict__ A, const ushort* __restrict__ W,
    ushort* __restrict__ C, int M, int N, int K,
    const float* __restrict__ pb1, const float* __restrict__ pb2, float bscale)
{
  const int wave = threadIdx.x >> 6, lane = threadIdx.x & 63;
  const int task = blockIdx.x*4 + wave;
  const int NT = N >> 6;
  const int mt = task / NT, ng = task % NT;
  const int r = lane & 15, quad = lane >> 4;

  const ushort* ap = A + (size_t)(mt*64 + r)*K + quad*8;
  const ushort* wp = W + (size_t)(ng*64 + r)*K + quad*8;
  f32x4 acc[4][4];
  #pragma unroll
  for (int t = 0; t < 4; ++t)
    #pragma unroll
    for (int j = 0; j < 4; ++j) acc[t][j] = (f32x4){0,0,0,0};

  #pragma unroll 2
  for (int k0 = 0; k0 < K; k0 += 32){
    short8 a0 = *(const short8*)(ap + k0);
    short8 a1 = *(const short8*)(ap + (size_t)16*K + k0);
    short8 a2 = *(const short8*)(ap + (size_t)32*K + k0);
    short8 a3 = *(const short8*)(ap + (size_t)48*K + k0);
    short8 b0 = *(const short8*)(wp + k0);
    short8 b1 = *(const short8*)(wp + (size_t)16*K + k0);
    short8 b2 = *(const short8*)(wp + (size_t)32*K + k0);
    short8 b3 = *(const short8*)(wp + (size_t)48*K + k0);
    acc[0][0] = __builtin_amdgcn_mfma_f32_16x16x32_bf16(a0, b0, acc[0][0], 0, 0, 0);
    acc[0][1] = __builtin_amdgcn_mfma_f32_16x16x32_bf16(a0, b1, acc[0][1], 0, 0, 0);
    acc[0][2] = __builtin_amdgcn_mfma_f32_16x16x32_bf16(a0, b2, acc[0][2], 0, 0, 0);
    acc[0][3] = __builtin_amdgcn_mfma_f32_16x16x32_bf16(a0, b3, acc[0][3], 0, 0, 0);
    acc[1][0] = __builtin_amdgcn_mfma_f32_16x16x32_bf16(a1, b0, acc[1][0], 0, 0, 0);
    acc[1][1] = __builtin_amdgcn_mfma_f32_16x16x32_bf16(a1, b1, acc[1][1], 0, 0, 0);
    acc[1][2] = __builtin_amdgcn_mfma_f32_16x16x32_bf16(a1, b2, acc[1][2], 0, 0, 0);
    acc[1][3] = __builtin_amdgcn_mfma_f32_16x16x32_bf16(a1, b3, acc[1][3], 0, 0, 0);
    acc[2][0] = __builtin_amdgcn_mfma_f32_16x16x32_bf16(a2, b0, acc[2][0], 0, 0, 0);
    acc[2][1] = __builtin_amdgcn_mfma_f32_16x16x32_bf16(a2, b1, acc[2][1], 0, 0, 0);
    acc[2][2] = __builtin_amdgcn_mfma_f32_16x16x32_bf16(a2, b2, acc[2][2], 0, 0, 0);
    acc[2][3] = __builtin_amdgcn_mfma_f32_16x16x32_bf16(a2, b3, acc[2][3], 0, 0, 0);
    acc[3][0] = __builtin_amdgcn_mfma_f32_16x16x32_bf16(a3, b0, acc[3][0], 0, 0, 0);
    acc[3][1] = __builtin_amdgcn_mfma_f32_16x16x32_bf16(a3, b1, acc[3][1], 0, 0, 0);
    acc[3][2] = __builtin_amdgcn_mfma_f32_16x16x32_bf16(a3, b2, acc[3][2], 0, 0, 0);
    acc[3][3] = __builtin_amdgcn_mfma_f32_16x16x32_bf16(a3, b3, acc[3][3], 0, 0, 0);
  }
  #pragma unroll
  for (int j = 0; j < 4; ++j){
    const int nn = ng*64 + j*16 + r;
    float bias = 0.f;
    if (pb1) bias += pb1[nn];
    if (pb2) bias += pb2[nn];
    bias *= bscale;
    #pragma unroll
    for (int t = 0; t < 4; ++t){
      #pragma unroll
      for (int i = 0; i < 4; ++i){
        const int mm = mt*64 + t*16 + quad*4 + i;
        C[(size_t)mm*N + nn] = f2b(acc[t][j][i] + bias);
      }
    }
  }
}

// ================= chunked scan, MFMA, 32 batches/block =================
// grid = 256 blocks = 128 chunks x 2 batch-groups of 32 batches; 8 waves/block.
template<bool FULL>
__global__ __launch_bounds__(512) void scan_mfma(
    const ushort* __restrict__ U,     // (B,S,H) bf16
    const ushort* __restrict__ G,     // (H,H) bf16 row-major [n][m] = bf16(0.1*Wh)
    const float* __restrict__ S,      // (B,NC,H) chunk-entry states (FULL only)
    float* __restrict__ Z,            // (B,NC,H) chunk-end states (!FULL only)
    ushort* __restrict__ nh)          // (B,S,H) bf16 (FULL only)
{
  const int c  = blockIdx.x & (kNC - 1);   // 0..127
  const int b0 = (blockIdx.x >> 7) * 32;   // 0 or 32
  const int wave = threadIdx.x >> 6, lane = threadIdx.x & 63;
  const int r = lane & 15, quad = lane >> 4;
  const int wbase = wave * 64;
  const int colq = quad * 4;

  __shared__ __align__(16) ushort hiL[2][32*kH];
  __shared__ __align__(16) ushort loL[2][32*kH];

  // swizzled byte offset into a [32][512] bf16 tile
  #define SWZ(row, bytecol) ((row)*1024 + ((bytecol) ^ (((row)&7) << 4)))

  const ushort* gp0 = G + (size_t)(wbase +  0 + r)*kH + quad*8;
  const ushort* gp1 = G + (size_t)(wbase + 16 + r)*kH + quad*8;
  const ushort* gp2 = G + (size_t)(wbase + 32 + r)*kH + quad*8;
  const ushort* gp3 = G + (size_t)(wbase + 48 + r)*kH + quad*8;

  float st[2][4][4];
  #pragma unroll
  for (int bt = 0; bt < 2; ++bt)
    #pragma unroll
    for (int t = 0; t < 4; ++t){
      if (FULL){
        const float4 s4 = *(const float4*)&S[((size_t)(b0 + bt*16 + r)*kNC + c)*kH
                                             + wbase + t*16 + colq];
        st[bt][t][0] = s4.x; st[bt][t][1] = s4.y;
        st[bt][t][2] = s4.z; st[bt][t][3] = s4.w;
      } else {
        st[bt][t][0] = st[bt][t][1] = st[bt][t][2] = st[bt][t][3] = 0.f;
      }
    }

  #pragma unroll
  for (int bt = 0; bt < 2; ++bt)
    #pragma unroll
    for (int t = 0; t < 4; ++t){
      ushort h[4], l[4];
      #pragma unroll
      for (int i = 0; i < 4; ++i){
        h[i] = f2b(st[bt][t][i]);
        l[i] = f2b(st[bt][t][i] - b2f(h[i]));
      }
      uint2 hw, lw;
      hw.x = (unsigned)h[0] | ((unsigned)h[1] << 16);
      hw.y = (unsigned)h[2] | ((unsigned)h[3] << 16);
      lw.x = (unsigned)l[0] | ((unsigned)l[1] << 16);
      lw.y = (unsigned)l[2] | ((unsigned)l[3] << 16);
      const int bc = (wbase + t*16 + colq) * 2;
      *(uint2*)((char*)hiL[0] + SWZ(bt*16 + r, bc)) = hw;
      *(uint2*)((char*)loL[0] + SWZ(bt*16 + r, bc)) = lw;
    }
  __syncthreads();

  const size_t ub0 = (size_t)(b0 +  0 + r)*kS*kH;
  const size_t ub1 = (size_t)(b0 + 16 + r)*kS*kH;
  int cur = 0;

  for (int jj = 0; jj < kC; ++jj){
    const int tt = c*kC + jj;

    uint2 uv[2][4];
    #pragma unroll
    for (int t = 0; t < 4; ++t){
      uv[0][t] = *(const uint2*)&U[ub0 + (size_t)tt*kH + wbase + t*16 + colq];
      uv[1][t] = *(const uint2*)&U[ub1 + (size_t)tt*kH + wbase + t*16 + colq];
    }

    const char* rdHi = (const char*)hiL[cur];
    const char* rdLo = (const char*)loL[cur];
    char* wrHi = (char*)hiL[cur ^ 1];
    char* wrLo = (char*)loL[cur ^ 1];

    f32x4 ah[2][4], al[2][4];
    #pragma unroll
    for (int bt = 0; bt < 2; ++bt)
      #pragma unroll
      for (int t = 0; t < 4; ++t){ ah[bt][t] = (f32x4){0,0,0,0}; al[bt][t] = (f32x4){0,0,0,0}; }

    __builtin_amdgcn_s_setprio(1);
    #pragma unroll 2
    for (int k0 = 0; k0 < kH; k0 += 32){
      const int rb = k0*2 + quad*16;   // 16B-aligned, swizzle-safe
      const short8 bh0 = *(const short8*)(rdHi + SWZ( 0 + r, rb));
      const short8 bl0 = *(const short8*)(rdLo + SWZ( 0 + r, rb));
      const short8 bh1 = *(const short8*)(rdHi + SWZ(16 + r, rb));
      const short8 bl1 = *(const short8*)(rdLo + SWZ(16 + r, rb));
      const short8 g0 = *(const short8*)(gp0 + k0);
      const short8 g1 = *(const short8*)(gp1 + k0);
      const short8 g2 = *(const short8*)(gp2 + k0);
      const short8 g3 = *(const short8*)(gp3 + k0);
      ah[0][0] = __builtin_amdgcn_mfma_f32_16x16x32_bf16(g0, bh0, ah[0][0], 0, 0, 0);
      ah[0][1] = __builtin_amdgcn_mfma_f32_16x16x32_bf16(g1, bh0, ah[0][1], 0, 0, 0);
      ah[0][2] = __builtin_amdgcn_mfma_f32_16x16x32_bf16(g2, bh0, ah[0][2], 0, 0, 0);
      ah[0][3] = __builtin_amdgcn_mfma_f32_16x16x32_bf16(g3, bh0, ah[0][3], 0, 0, 0);
      al[0][0] = __builtin_amdgcn_mfma_f32_16x16x32_bf16(g0, bl0, al[0][0], 0, 0, 0);
      al[0][1] = __builtin_amdgcn_mfma_f32_16x16x32_bf16(g1, bl0, al[0][1], 0, 0, 0);
      al[0][2] = __builtin_amdgcn_mfma_f32_16x16x32_bf16(g2, bl0, al[0][2], 0, 0, 0);
      al[0][3] = __builtin_amdgcn_mfma_f32_16x16x32_bf16(g3, bl0, al[0][3], 0, 0, 0);
      ah[1][0] = __builtin_amdgcn_mfma_f32_16x16x32_bf16(g0, bh1, ah[1][0], 0, 0, 0);
      ah[1][1] = __builtin_amdgcn_mfma_f32_16x16x32_bf16(g1, bh1, ah[1][1], 0, 0, 0);
      ah[1][2] = __builtin_amdgcn_mfma_f32_16x16x32_bf16(g2, bh1, ah[1][2], 0, 0, 0);
      ah[1][3] = __builtin_amdgcn_mfma_f32_16x16x32_bf16(g3, bh1, ah[1][3], 0, 0, 0);
      al[1][0] = __builtin_amdgcn_mfma_f32_16x16x32_bf16(g0, bl1, al[1][0], 0, 0, 0);
      al[1][1] = __builtin_amdgcn_mfma_f32_16x16x32_bf16(g1, bl1, al[1][1], 0, 0, 0);
      al[1][2] = __builtin_amdgcn_mfma_f32_16x16x32_bf16(g2, bl1, al[1][2], 0, 0, 0);
      al[1][3] = __builtin_amdgcn_mfma_f32_16x16x32_bf16(g3, bl1, al[1][3], 0, 0, 0);
    }
    __builtin_amdgcn_s_setprio(0);

    #pragma unroll
    for (int bt = 0; bt < 2; ++bt){
      const size_t ub = bt ? ub1 : ub0;
      #pragma unroll
      for (int t = 0; t < 4; ++t){
        const f32x4 acs = ah[bt][t] + al[bt][t];
        float u0, u1, u2, u3;
        unpack2(uv[bt][t].x, u0, u1); unpack2(uv[bt][t].y, u2, u3);
        const float n0 = 0.9f*st[bt][t][0] + u0 + acs[0];
        const float n1 = 0.9f*st[bt][t][1] + u1 + acs[1];
        const float n2 = 0.9f*st[bt][t][2] + u2 + acs[2];
        const float n3 = 0.9f*st[bt][t][3] + u3 + acs[3];
        st[bt][t][0] = n0; st[bt][t][1] = n1;
        st[bt][t][2] = n2; st[bt][t][3] = n3;
        const ushort h0 = f2b(n0), h1 = f2b(n1), h2 = f2b(n2), h3 = f2b(n3);
        const ushort l0 = f2b(n0 - b2f(h0)), l1 = f2b(n1 - b2f(h1));
        const ushort l2 = f2b(n2 - b2f(h2)), l3 = f2b(n3 - b2f(h3));
        uint2 hw, lw;
        hw.x = (unsigned)h0 | ((unsigned)h1 << 16);
        hw.y = (unsigned)h2 | ((unsigned)h3 << 16);
        lw.x = (unsigned)l0 | ((unsigned)l1 << 16);
        lw.y = (unsigned)l2 | ((unsigned)l3 << 16);
        const int bc = (wbase + t*16 + colq) * 2;
        *(uint2*)(wrHi + SWZ(bt*16 + r, bc)) = hw;
        *(uint2*)(wrLo + SWZ(bt*16 + r, bc)) = lw;
        if (FULL)
          *(uint2*)&nh[ub + (size_t)tt*kH + wbase + t*16 + colq] = hw;
      }
    }
    __syncthreads();   // single barrier: writes to cur^1 visible, reads of cur done
    cur ^= 1;
  }

  if (!FULL){
    #pragma unroll
    for (int bt = 0; bt < 2; ++bt)
      #pragma unroll
      for (int t = 0; t < 4; ++t){
        float4 z4; z4.x = st[bt][t][0]; z4.y = st[bt][t][1];
        z4.z = st[bt][t][2]; z4.w = st[bt][t][3];
        *(float4*)&Z[((size_t)(b0 + bt*16 + r)*kNC + c)*kH
                     + wbase + t*16 + colq] = z4;
      }
  }
  #undef SWZ
}

// ================= three-level boundary scan (fp32, 4 batches/block) =========
// Proven coalesced matvec: thread = output col n; A row read coalesced;
// s[bi][m] broadcast from LDS. 4 batches share each A-stream (4x less traffic).

// (a) P8[b][cc] = zero-init state through chunks cc*kSC .. +kSC-1 (A^4 per chunk)
__global__ __launch_bounds__(512) void bscan_a(
    const float* __restrict__ A4, const float* __restrict__ Z,
    float* __restrict__ P8)
{
  const int bg = blockIdx.x >> 4, cc = blockIdx.x & 15;   // 256 blocks = 16 bg x 16 sc
  const int n = threadIdx.x;
  __shared__ float s[4][kH];
  #pragma unroll
  for (int bi = 0; bi < 4; ++bi)
    s[bi][n] = Z[((size_t)(bg*4 + bi)*kNC + cc*kSC)*kH + n];
  __syncthreads();
  for (int j = 1; j < kSC; ++j){
    float a0 = Z[((size_t)(bg*4 + 0)*kNC + cc*kSC + j)*kH + n];
    float a1 = Z[((size_t)(bg*4 + 1)*kNC + cc*kSC + j)*kH + n];
    float a2 = Z[((size_t)(bg*4 + 2)*kNC + cc*kSC + j)*kH + n];
    float a3 = Z[((size_t)(bg*4 + 3)*kNC + cc*kSC + j)*kH + n];
    for (int m = 0; m < kH; m += 4){
      const float am0 = A4[(size_t)m*kH + n],     am1 = A4[(size_t)(m+1)*kH + n];
      const float am2 = A4[(size_t)(m+2)*kH + n], am3 = A4[(size_t)(m+3)*kH + n];
      const float4 s0 = *(const float4*)&s[0][m];
      const float4 s1 = *(const float4*)&s[1][m];
      const float4 s2 = *(const float4*)&s[2][m];
      const float4 s3 = *(const float4*)&s[3][m];
      a0 += s0.x*am0 + s0.y*am1 + s0.z*am2 + s0.w*am3;
      a1 += s1.x*am0 + s1.y*am1 + s1.z*am2 + s1.w*am3;
      a2 += s2.x*am0 + s2.y*am1 + s2.z*am2 + s2.w*am3;
      a3 += s3.x*am0 + s3.y*am1 + s3.z*am2 + s3.w*am3;
    }
    __syncthreads();
    s[0][n] = a0; s[1][n] = a1; s[2][n] = a2; s[3][n] = a3;
    __syncthreads();
  }
  #pragma unroll
  for (int bi = 0; bi < 4; ++bi)
    P8[((size_t)(bg*4 + bi)*kNSC + cc)*kH + n] = s[bi][n];
}

// (h1) Ph[b][hc] = zero-init state through super-chunks hc*kHC .. +kHC-1 (A^32)
__global__ __launch_bounds__(512) void bscan_h1(
    const float* __restrict__ A32, const float* __restrict__ P8,
    float* __restrict__ Ph)
{
  const int bg = blockIdx.x >> 2, hc = blockIdx.x & 3;    // 64 blocks = 16 bg x 4 hc
  const int n = threadIdx.x;
  __shared__ float s[4][kH];
  #pragma unroll
  for (int bi = 0; bi < 4; ++bi)
    s[bi][n] = P8[((size_t)(bg*4 + bi)*kNSC + hc*kHC)*kH + n];
  __syncthreads();
  for (int j = 1; j < kHC; ++j){
    float a0 = P8[((size_t)(bg*4 + 0)*kNSC + hc*kHC + j)*kH + n];
    float a1 = P8[((size_t)(bg*4 + 1)*kNSC + hc*kHC + j)*kH + n];
    float a2 = P8[((size_t)(bg*4 + 2)*kNSC + hc*kHC + j)*kH + n];
    float a3 = P8[((size_t)(bg*4 + 3)*kNSC + hc*kHC + j)*kH + n];
    for (int m = 0; m < kH; m += 4){
      const float am0 = A32[(size_t)m*kH + n],     am1 = A32[(size_t)(m+1)*kH + n];
      const float am2 = A32[(size_t)(m+2)*kH + n], am3 = A32[(size_t)(m+3)*kH + n];
      const float4 s0 = *(const float4*)&s[0][m];
      const float4 s1 = *(const float4*)&s[1][m];
      const float4 s2 = *(const float4*)&s[2][m];
      const float4 s3 = *(const float4*)&s[3][m];
      a0 += s0.x*am0 + s0.y*am1 + s0.z*am2 + s0.w*am3;
      a1 += s1.x*am0 + s1.y*am1 + s1.z*am2 + s1.w*am3;
      a2 += s2.x*am0 + s2.y*am1 + s2.z*am2 + s2.w*am3;
      a3 += s3.x*am0 + s3.y*am1 + s3.z*am2 + s3.w*am3;
    }
    __syncthreads();
    s[0][n] = a0; s[1][n] = a1; s[2][n] = a2; s[3][n] = a3;
    __syncthreads();
  }
  #pragma unroll
  for (int bi = 0; bi < 4; ++bi)
    Ph[((size_t)(bg*4 + bi)*kNHC + hc)*kH + n] = s[bi][n];
}

// (h2) Sh[b][hc] = state entering hyper-chunk hc (A^128 recursion), 1 batch/block
__global__ __launch_bounds__(512) void bscan_h2(
    const float* __restrict__ A128, const float* __restrict__ Ph,
    float* __restrict__ Sh)
{
  const int b = blockIdx.x, n = threadIdx.x;             // 64 blocks
  __shared__ float s[kH];
  Sh[((size_t)b*kNHC + 0)*kH + n] = 0.f;
  s[n] = Ph[((size_t)b*kNHC + 0)*kH + n];
  Sh[((size_t)b*kNHC + 1)*kH + n] = s[n];
  __syncthreads();
  for (int hc = 1; hc < kNHC - 1; ++hc){
    float acc = Ph[((size_t)b*kNHC + hc)*kH + n];
    for (int m = 0; m < kH; m += 4){
      const float4 sv = *(const float4*)&s[m];
      acc += sv.x*A128[(size_t)m*kH + n]     + sv.y*A128[(size_t)(m+1)*kH + n]
           + sv.z*A128[(size_t)(m+2)*kH + n] + sv.w*A128[(size_t)(m+3)*kH + n];
    }
    __syncthreads();
    s[n] = acc;
    Sh[((size_t)b*kNHC + hc + 1)*kH + n] = acc;
    __syncthreads();
  }
}

// (h3) S2[b][cc] = state entering super-chunk cc within each hyper-chunk (A^32)
__global__ __launch_bounds__(512) void bscan_h3(
    const float* __restrict__ A32, const float* __restrict__ P8,
    const float* __restrict__ Sh, float* __restrict__ S2)
{
  const int bg = blockIdx.x >> 2, hc = blockIdx.x & 3;    // 64 blocks = 16 bg x 4 hc
  const int n = threadIdx.x;
  __shared__ float s[4][kH];
  #pragma unroll
  for (int bi = 0; bi < 4; ++bi){
    s[bi][n] = Sh[((size_t)(bg*4 + bi)*kNHC + hc)*kH + n];
    S2[((size_t)(bg*4 + bi)*kNSC + hc*kHC)*kH + n] = s[bi][n];
  }
  __syncthreads();
  for (int j = 0; j < kHC - 1; ++j){
    float a0 = P8[((size_t)(bg*4 + 0)*kNSC + hc*kHC + j)*kH + n];
    float a1 = P8[((size_t)(bg*4 + 1)*kNSC + hc*kHC + j)*kH + n];
    float a2 = P8[((size_t)(bg*4 + 2)*kNSC + hc*kHC + j)*kH + n];
    float a3 = P8[((size_t)(bg*4 + 3)*kNSC + hc*kHC + j)*kH + n];
    for (int m = 0; m < kH; m += 4){
      const float am0 = A32[(size_t)m*kH + n],     am1 = A32[(size_t)(m+1)*kH + n];
      const float am2 = A32[(size_t)(m+2)*kH + n], am3 = A32[(size_t)(m+3)*kH + n];
      const float4 s0 = *(const float4*)&s[0][m];
      const float4 s1 = *(const float4*)&s[1][m];
      const float4 s2 = *(const float4*)&s[2][m];
      const float4 s3 = *(const float4*)&s[3][m];
      a0 += s0.x*am0 + s0.y*am1 + s0.z*am2 + s0.w*am3;
      a1 += s1.x*am0 + s1.y*am1 + s1.z*am2 + s1.w*am3;
      a2 += s2.x*am0 + s2.y*am1 + s2.z*am2 + s2.w*am3;
      a3 += s3.x*am0 + s3.y*am1 + s3.z*am2 + s3.w*am3;
    }
    __syncthreads();
    #pragma unroll
    for (int bi = 0; bi < 4; ++bi){
      const float av = bi == 0 ? a0 : bi == 1 ? a1 : bi == 2 ? a2 : a3;
      s[bi][n] = av;
      S2[((size_t)(bg*4 + bi)*kNSC + hc*kHC + j + 1)*kH + n] = av;
    }
    __syncthreads();
  }
}

// (c) emit all chunk-entry states within each super-chunk (A^4)
__global__ __launch_bounds__(512) void bscan_c(
    const float* __restrict__ A4, const float* __restrict__ Z,
    const float* __restrict__ S2, float* __restrict__ S)
{
  const int bg = blockIdx.x >> 4, cc = blockIdx.x & 15;   // 256 blocks = 16 bg x 16 sc
  const int n = threadIdx.x;
  __shared__ float s[4][kH];
  #pragma unroll
  for (int bi = 0; bi < 4; ++bi){
    s[bi][n] = S2[((size_t)(bg*4 + bi)*kNSC + cc)*kH + n];
    S[((size_t)(bg*4 + bi)*kNC + cc*kSC)*kH + n] = s[bi][n];
  }
  __syncthreads();
  for (int j = 0; j < kSC - 1; ++j){
    float a0 = Z[((size_t)(bg*4 + 0)*kNC + cc*kSC + j)*kH + n];
    float a1 = Z[((size_t)(bg*4 + 1)*kNC + cc*kSC + j)*kH + n];
    float a2 = Z[((size_t)(bg*4 + 2)*kNC + cc*kSC + j)*kH + n];
    float a3 = Z[((size_t)(bg*4 + 3)*kNC + cc*kSC + j)*kH + n];
    for (int m = 0; m < kH; m += 4){
      const float am0 = A4[(size_t)m*kH + n],     am1 = A4[(size_t)(m+1)*kH + n];
      const float am2 = A4[(size_t)(m+2)*kH + n], am3 = A4[(size_t)(m+3)*kH + n];
      const float4 s0 = *(const float4*)&s[0][m];
      const float4 s1 = *(const float4*)&s[1][m];
      const float4 s2 = *(const float4*)&s[2][m];
      const float4 s3 = *(const float4*)&s[3][m];
      a0 += s0.x*am0 + s0.y*am1 + s0.z*am2 + s0.w*am3;
      a1 += s1.x*am0 + s1.y*am1 + s1.z*am2 + s1.w*am3;
      a2 += s2.x*am0 + s2.y*am1 + s2.z*am2 + s2.w*am3;
      a3 += s3.x*am0 + s3.y*am1 + s3.z*am2 + s3.w*am3;
    }
    __syncthreads();
    #pragma unroll
    for (int bi = 0; bi < 4; ++bi){
      const float av = bi == 0 ? a0 : bi == 1 ? a1 : bi == 2 ? a2 : a3;
      s[bi][n] = av;
      S[((size_t)(bg*4 + bi)*kNC + cc*kSC + j + 1)*kH + n] = av;
    }
    __syncthreads();
  }
}

// ---------------- LayerNorm rows (in place on bf16) ----------------
__global__ __launch_bounds__(512) void ln_rows(
    ushort* __restrict__ act, const float* __restrict__ g, const float* __restrict__ bta)
{
  const size_t row = blockIdx.x;
  const int n = threadIdx.x, wid = n >> 6, lane = n & 63;
  __shared__ float red[16];
  const float y = b2f(act[row*kH + n]);
  float s1 = y, s2 = y*y;
  #pragma unroll
  for (int off = 32; off; off >>= 1){
    s1 += __shfl_down(s1, off); s2 += __shfl_down(s2, off);
  }
  if (lane == 0){ red[wid] = s1; red[8 + wid] = s2; }
  __syncthreads();
  float m = 0.f, q = 0.f;
  #pragma unroll
  for (int i = 0; i < 8; ++i){ m += red[i]; q += red[8+i]; }
  m *= (1.f/kH); q *= (1.f/kH);
  const float var = q - m*m;
  const float hv = (y - m) * rsqrtf(var + EPS) * g[n] + bta[n];
  act[row*kH + n] = f2b(hv);
}

// ---------------- seqmean (fp32) from bf16 act ----------------
__global__ __launch_bounds__(512) void seqmean_k(
    const ushort* __restrict__ act, float* __restrict__ seqmean)
{
  const int b = blockIdx.x, n = threadIdx.x;
  float acc = 0.f;
  for (int t = 0; t < kS; ++t) acc += b2f(act[((size_t)b*kS + t)*kH + n]);
  seqmean[(size_t)b*kH + n] = acc * (1.f/kS);
}

// ---------------- MFMA flash attention on precomputed qkv (bf16) -------------
__global__ __launch_bounds__(512) void attn_chunk(
    const ushort* __restrict__ qkv,   // (16*S, 3H) bf16
    float* __restrict__ aomean, int b0)
{
  const int bb = blockIdx.x >> 5;          // batch within chunk
  const int h  = (blockIdx.x >> 2) & 7;    // head
  const int qt = blockIdx.x & 3;           // 128-query tile
  const int tid = threadIdx.x, wave = tid >> 6, lane = tid & 63;
  const int r = lane & 15, quad = lane >> 4;

  __shared__ __align__(16) ushort kt[64][72];      // [key][dim]
  __shared__ __align__(16) ushort vt[64][72];      // transposed: [dim][key]
  __shared__ ushort pt[8][16][72];                 // per-wave P [q_local][key]
  __shared__ float aom[kDH];
  if (tid < kDH) aom[tid] = 0.f;

  const int q0 = qt*128 + wave*16;
  short8 qa0, qa1;
  {
    const ushort* qp = qkv + ((size_t)bb*kS + q0 + r)*(3*kH) + h*kDH + quad*8;
    qa0 = *(const short8*)qp;
    qa1 = *(const short8*)(qp + 32);
  }

  f32x4 oc0={0,0,0,0}, oc1={0,0,0,0}, oc2={0,0,0,0}, oc3={0,0,0,0};
  float mRow[4] = {-1e30f,-1e30f,-1e30f,-1e30f};
  float lRow[4] = {0.f,0.f,0.f,0.f};

  const int srow = tid & 63;
  const int sd0  = (tid >> 6) * 8;

  for (int kt0 = 0; kt0 < kS/64; ++kt0){
    {
      const size_t rbase = ((size_t)bb*kS + kt0*64 + srow)*(3*kH) + h*kDH + sd0;
      *(uint4*)&kt[srow][sd0] = *(const uint4*)(qkv + rbase + kH);
      uint4 v4 = *(const uint4*)(qkv + rbase + 2*kH);
      const ushort* vs = (const ushort*)&v4;
      #pragma unroll
      for (int ii = 0; ii < 8; ++ii) vt[sd0 + ii][srow] = vs[ii];
    }
    __syncthreads();

    f32x4 ac0={0,0,0,0}, ac1={0,0,0,0}, ac2={0,0,0,0}, ac3={0,0,0,0};
    #pragma unroll
    for (int k0 = 0; k0 < 2; ++k0){
      const short8 av = k0 ? qa1 : qa0;
      const short8 b0v = *(const short8*)&kt[ 0 + r][k0*32 + quad*8];
      const short8 b1v = *(const short8*)&kt[16 + r][k0*32 + quad*8];
      const short8 b2v = *(const short8*)&kt[32 + r][k0*32 + quad*8];
      const short8 b3v = *(const short8*)&kt[48 + r][k0*32 + quad*8];
      ac0 = __builtin_amdgcn_mfma_f32_16x16x32_bf16(av, b0v, ac0, 0, 0, 0);
      ac1 = __builtin_amdgcn_mfma_f32_16x16x32_bf16(av, b1v, ac1, 0, 0, 0);
      ac2 = __builtin_amdgcn_mfma_f32_16x16x32_bf16(av, b2v, ac2, 0, 0, 0);
      ac3 = __builtin_amdgcn_mfma_f32_16x16x32_bf16(av, b3v, ac3, 0, 0, 0);
    }
    const f32x4 sc0 = ac0 * 0.125f, sc1 = ac1 * 0.125f,
                sc2 = ac2 * 0.125f, sc3 = ac3 * 0.125f;

    float p0[4], p1[4], p2[4], p3[4];
    #pragma unroll
    for (int i = 0; i < 4; ++i){
      float mx = fmaxf(fmaxf(sc0[i], sc1[i]), fmaxf(sc2[i], sc3[i]));
      #pragma unroll
      for (int off = 1; off < 16; off <<= 1) mx = fmaxf(mx, __shfl_xor(mx, off));
      const float nm = fmaxf(mRow[i], mx);
      const float corr = __expf(mRow[i] - nm);
      mRow[i] = nm;
      p0[i] = __expf(sc0[i] - nm); p1[i] = __expf(sc1[i] - nm);
      p2[i] = __expf(sc2[i] - nm); p3[i] = __expf(sc3[i] - nm);
      float rs = p0[i] + p1[i] + p2[i] + p3[i];
      #pragma unroll
      for (int off = 1; off < 16; off <<= 1) rs += __shfl_xor(rs, off);
      lRow[i] = lRow[i]*corr + rs;
      oc0[i] *= corr; oc1[i] *= corr; oc2[i] *= corr; oc3[i] *= corr;
    }

    #pragma unroll
    for (int i = 0; i < 4; ++i){
      pt[wave][quad*4 + i][ 0 + r] = f2b(p0[i]);
      pt[wave][quad*4 + i][16 + r] = f2b(p1[i]);
      pt[wave][quad*4 + i][32 + r] = f2b(p2[i]);
      pt[wave][quad*4 + i][48 + r] = f2b(p3[i]);
    }

    #pragma unroll
    for (int k0 = 0; k0 < 2; ++k0){
      const short8 pa  = *(const short8*)&pt[wave][r][k0*32 + quad*8];
      const short8 v0v = *(const short8*)&vt[ 0 + r][k0*32 + quad*8];
      const short8 v1v = *(const short8*)&vt[16 + r][k0*32 + quad*8];
      const short8 v2v = *(const short8*)&vt[32 + r][k0*32 + quad*8];
      const short8 v3v = *(const short8*)&vt[48 + r][k0*32 + quad*8];
      oc0 = __builtin_amdgcn_mfma_f32_16x16x32_bf16(pa, v0v, oc0, 0, 0, 0);
      oc1 = __builtin_amdgcn_mfma_f32_16x16x32_bf16(pa, v1v, oc1, 0, 0, 0);
      oc2 = __builtin_amdgcn_mfma_f32_16x16x32_bf16(pa, v2v, oc2, 0, 0, 0);
      oc3 = __builtin_amdgcn_mfma_f32_16x16x32_bf16(pa, v3v, oc3, 0, 0, 0);
    }
    __syncthreads();
  }

  float inv[4];
  #pragma unroll
  for (int i = 0; i < 4; ++i) inv[i] = 1.f / lRow[i];
  {
    float v;
    v = oc0[0]*inv[0] + oc0[1]*inv[1] + oc0[2]*inv[2] + oc0[3]*inv[3];
    v += __shfl_xor(v, 16); v += __shfl_xor(v, 32);
    if (quad == 0) atomicAdd(&aom[ 0 + r], v);
    v = oc1[0]*inv[0] + oc1[1]*inv[1] + oc1[2]*inv[2] + oc1[3]*inv[3];
    v += __shfl_xor(v, 16); v += __shfl_xor(v, 32);
    if (quad == 0) atomicAdd(&aom[16 + r], v);
    v = oc2[0]*inv[0] + oc2[1]*inv[1] + oc2[2]*inv[2] + oc2[3]*inv[3];
    v += __shfl_xor(v, 16); v += __shfl_xor(v, 32);
    if (quad == 0) atomicAdd(&aom[32 + r], v);
    v = oc3[0]*inv[0] + oc3[1]*inv[1] + oc3[2]*inv[2] + oc3[3]*inv[3];
    v += __shfl_xor(v, 16); v += __shfl_xor(v, 32);
    if (quad == 0) atomicAdd(&aom[48 + r], v);
  }
  __syncthreads();
  if (tid < kDH)
    atomicAdd(&aomean[(size_t)(b0 + bb)*kH + h*kDH + tid], aom[tid] * (1.f/kS));
}

// ---- pooled = seqmean + aomean@out_w^T + out_b (fp32) ----
__global__ __launch_bounds__(512) void pooled_kernel(
    const float* __restrict__ seqmean, const float* __restrict__ aomean,
    const float* __restrict__ outw, const float* __restrict__ outb,
    float* __restrict__ pooled)
{
  const int b = blockIdx.x, n = threadIdx.x;
  __shared__ float a[kH];
  a[n] = aomean[(size_t)b*kH + n];
  __syncthreads();
  const float* w = outw + (size_t)n*kH;
  float acc = outb[n];
  for (int m = 0; m < kH; ++m) acc += w[m] * a[m];
  pooled[(size_t)b*kH + n] = seqmean[(size_t)b*kH + n] + acc;
}

// ---------------- heads (fp32, validated) ----------------
__global__ __launch_bounds__(256) void heads_kernel(
    const float* __restrict__ pooled,
    const float* Wd1, const float* bd1, const float* Wd2, const float* bd2,
    const float* Wd3, const float* bd3,
    const float* Wq1, const float* bq1, const float* Wq2, const float* bq2,
    const float* Wq3, const float* bq3,
    const float* Wc1, const float* bc1, const float* Wc2, const float* bc2,
    float* __restrict__ out)
{
  const int b = blockIdx.x, tid = threadIdx.x;
  __shared__ float p[kH];
  __shared__ float a1d[256], a1q[256], a1c[256];
  __shared__ float a2d[128], a2q[128];
  p[tid]       = pooled[(size_t)b*kH + tid];
  p[tid + 256] = pooled[(size_t)b*kH + tid + 256];
  __syncthreads();
  {
    const float *w1 = Wd1 + (size_t)tid*kH, *w2 = Wq1 + (size_t)tid*kH,
                *w3 = Wc1 + (size_t)tid*kH;
    float v1 = bd1[tid], v2 = bq1[tid], v3 = bc1[tid];
    for (int m = 0; m < kH; ++m){
      v1 += w1[m]*p[m]; v2 += w2[m]*p[m]; v3 += w3[m]*p[m];
    }
    a1d[tid] = fmaxf(v1, 0.f); a1q[tid] = fmaxf(v2, 0.f); a1c[tid] = fmaxf(v3, 0.f);
  }
  __syncthreads();
  if (tid < 128){
    const float *w1 = Wd2 + (size_t)tid*256, *w2 = Wq2 + (size_t)tid*256;
    float v1 = bd2[tid], v2 = bq2[tid];
    for (int m = 0; m < 256; ++m){ v1 += w1[m]*a1d[m]; v2 += w2[m]*a1q[m]; }
    a2d[tid] = fmaxf(v1, 0.f); a2q[tid] = fmaxf(v2, 0.f);
  }
  __syncthreads();
  if (tid == 0){
    float d0 = bd3[0], d1 = bd3[1], pr = bq3[0], c = bc2[0];
    for (int m = 0; m < 128; ++m){
      d0 += Wd3[m]*a2d[m]; d1 += Wd3[128+m]*a2d[m]; pr += Wq3[m]*a2q[m];
    }
    for (int m = 0; m < 256; ++m) c += Wc2[m]*a1c[m];
    c = 1.f / (1.f + __expf(-c));
    out[2*b + 0]  = d0;
    out[2*b + 1]  = d1;
    out[2*kB + b] = pr;
    out[3*kB + b] = c;
  }
}

// ---------------- launch ----------------
extern "C" void kernel_launch(void* const* d_in, const int* in_sizes, int n_in,
                              void* d_out, int out_size, void* d_ws, size_t ws_size,
                              hipStream_t stream) {
  const float* x    = (const float*)d_in[0];
  const float* Win0 = (const float*)d_in[1];
  const float* bin0 = (const float*)d_in[2];
  const float* Wi   = (const float*)d_in[3];
  const float* bi   = (const float*)d_in[4];
  const float* Wh   = (const float*)d_in[5];
  const float* bh   = (const float*)d_in[6];
  const float* Wo   = (const float*)d_in[7];
  const float* bo   = (const float*)d_in[8];
  const float* lng  = (const float*)d_in[9];
  const float* lnb  = (const float*)d_in[10];
  const float* ipw  = (const float*)d_in[11];
  const float* ipb  = (const float*)d_in[12];
  const float* outw = (const float*)d_in[13];
  const float* outb = (const float*)d_in[14];

  char* wsb = (char*)d_ws;
  const size_t MB = 1u << 20;
  ushort* act   = (ushort*)(wsb);               // 32 MiB
  ushort* U     = (ushort*)(wsb + 32*MB);       // 32 MiB (reused as qkv)
  ushort* nh    = (ushort*)(wsb + 64*MB);       // 32 MiB
  ushort* wh_bf = (ushort*)(wsb + 96*MB);       // 2 MiB (0.1-scaled Wh, [n][m])
  ushort* wi_bf = (ushort*)(wsb + 98*MB);       // 2 MiB (0.1-scaled)
  ushort* wo_bf = (ushort*)(wsb + 100*MB);      // 2 MiB
  float*  Afp   = (float*)(wsb + 102*MB);       // 4 MiB (ends A^4)
  float*  Afp2  = (float*)(wsb + 106*MB);       // 4 MiB (ends A^32)
  float*  A128b = (float*)(wsb + 110*MB);       // 4 MiB (A^128)
  ushort* w0_bf = (ushort*)(wsb + 114*MB);      // 64 KiB
  ushort* ip_bf = (ushort*)(wsb + 114*MB + 65536);            // 1.5 MiB
  ushort* x_bf  = (ushort*)(wsb + 114*MB + 65536 + 1572864);  // 4 MiB
  float*  Apow  = (float*)x_bf;                 // power temp (after input gemm)
  // act dead-window overlays (between Wi-gemm read and Wo-gemm write):
  float*  Zb    = (float*)act;                  // 16 MiB (B*NC*H fp32, NC=128)
  float*  S     = (float*)(wsb + 16*MB);        // 16 MiB (chunk-entry states)
  // nh dead-window overlays (pre-FULL):
  float*  P8    = (float*)nh;                   // 2 MiB
  float*  S2    = (float*)(wsb + 66*MB);        // 2 MiB
  float*  Ph    = (float*)(wsb + 68*MB);        // 512 KiB
  float*  Sh    = (float*)(wsb + 69*MB);        // 512 KiB
  char*   tail  = wsb + 114*MB + 65536 + 1572864 + 4194304;
  float* seqmean = (float*)tail;
  float* aomean  = seqmean + (size_t)kB*kH;
  float* pooled  = aomean  + (size_t)kB*kH;
  ushort* qkv    = U;   // overlay: U dead after scan phase

  // ---- prep casts ----
  cast_scale<<<(kB*kS*kF + 255)/256, 256, 0, stream>>>(x, x_bf, kB*kS*kF, 1.f);
  cast_scale<<<(kH*kF + 255)/256, 256, 0, stream>>>(Win0, w0_bf, kH*kF, 1.f);
  cast_scale<<<(kL*kH*kH + 255)/256, 256, 0, stream>>>(Wi, wi_bf, kL*kH*kH, 0.1f);
  cast_scale<<<(kL*kH*kH + 255)/256, 256, 0, stream>>>(Wo, wo_bf, kL*kH*kH, 1.f);
  cast_scale<<<(kL*kH*kH + 255)/256, 256, 0, stream>>>(Wh, wh_bf, kL*kH*kH, 0.1f);
  cast_scale<<<(3*kH*kH + 255)/256, 256, 0, stream>>>(ipw, ip_bf, 3*kH*kH, 1.f);
  prep_afp<<<(kL*kH*kH + 255)/256, 256, 0, stream>>>(Wh, Afp);
  // A^4 (ends in Afp)
  sqgemm<<<kL*64, 512, 0, stream>>>(Afp,  Afp2);   // A^2
  sqgemm<<<kL*64, 512, 0, stream>>>(Afp2, Afp);    // A^4  (keep)

  constexpr int M = kB*kS;   // 32768
  // input gemm consumes x_bf BEFORE Apow reuses its region
  gemm_bf16<<<(M/64)*(kH/64)/4, 256, 0, stream>>>(x_bf, w0_bf, act, M, kH, kF,
                                                  bin0, nullptr, 1.f);
  // A^32 (Afp2) and A^128 (A128b); temps use Afp2/x_bf
  sqgemm<<<kL*64, 512, 0, stream>>>(Afp,  Afp2);   // A^8
  sqgemm<<<kL*64, 512, 0, stream>>>(Afp2, Apow);   // A^16
  sqgemm<<<kL*64, 512, 0, stream>>>(Apow, Afp2);   // A^32 (keep)
  sqgemm<<<kL*64, 512, 0, stream>>>(Afp2, Apow);   // A^64
  sqgemm<<<kL*64, 512, 0, stream>>>(Apow, A128b);  // A^128 (keep)

  for (int l = 0; l < kL; ++l){
    gemm_bf16<<<(M/64)*(kH/64)/4, 256, 0, stream>>>(
        act, wi_bf + (size_t)l*kH*kH, U, M, kH, kH,
        bi + (size_t)l*kH, bh + (size_t)l*kH, 0.1f);
    scan_mfma<false><<<2*kNC, 512, 0, stream>>>(U, wh_bf + (size_t)l*kH*kH,
                                                nullptr, Zb, nullptr);
    bscan_a<<<(kB/4)*kNSC, 512, 0, stream>>>(Afp + (size_t)l*kH*kH, Zb, P8);
    bscan_h1<<<(kB/4)*kNHC, 512, 0, stream>>>(Afp2 + (size_t)l*kH*kH, P8, Ph);
    bscan_h2<<<kB, 512, 0, stream>>>(A128b + (size_t)l*kH*kH, Ph, Sh);
    bscan_h3<<<(kB/4)*kNHC, 512, 0, stream>>>(Afp2 + (size_t)l*kH*kH, P8, Sh, S2);
    bscan_c<<<(kB/4)*kNSC, 512, 0, stream>>>(Afp + (size_t)l*kH*kH, Zb, S2, S);
    scan_mfma<true><<<2*kNC, 512, 0, stream>>>(U, wh_bf + (size_t)l*kH*kH,
                                               S, nullptr, nh);
    gemm_bf16<<<(M/64)*(kH/64)/4, 256, 0, stream>>>(
        nh, wo_bf + (size_t)l*kH*kH, act, M, kH, kH,
        bo + (size_t)l*kH, nullptr, 1.f);
    ln_rows<<<M, kH, 0, stream>>>(act, lng + (size_t)l*kH, lnb + (size_t)l*kH);
  }

  seqmean_k<<<kB, kH, 0, stream>>>(act, seqmean);

  zero_f32<<<(kB*kH + 255)/256, 256, 0, stream>>>(aomean, kB*kH);
  for (int c = 0; c < 4; ++c){
    const int Mc = 16*kS;   // 8192
    gemm_bf16<<<(Mc/64)*(3*kH/64)/4, 256, 0, stream>>>(
        act + (size_t)c*Mc*kH, ip_bf, qkv, Mc, 3*kH, kH, ipb, nullptr, 1.f);
    attn_chunk<<<512, 512, 0, stream>>>(qkv, aomean, c*16);
  }

  pooled_kernel<<<kB, kH, 0, stream>>>(seqmean, aomean, outw, outb, pooled);

  heads_kernel<<<kB, 256, 0, stream>>>(pooled,
      (const float*)d_in[15], (const float*)d_in[16], (const float*)d_in[17],
      (const float*)d_in[18], (const float*)d_in[19], (const float*)d_in[20],
      (const float*)d_in[21], (const float*)d_in[22], (const float*)d_in[23],
      (const float*)d_in[24], (const float*)d_in[25], (const float*)d_in[26],
      (const float*)d_in[27], (const float*)d_in[28], (const float*)d_in[29],
      (const float*)d_in[30], (float*)d_out);
}

// Round 16
// 3334.249 us; speedup vs baseline: 1.2831x; 1.2078x over previous
//
#include <hip/hip_runtime.h>

// ---------------- problem constants ----------------
constexpr int kB  = 64;
constexpr int kS  = 512;
constexpr int kF  = 64;
constexpr int kH  = 512;
constexpr int kL  = 4;
constexpr int kDH = 64;
constexpr int kC  = 8;               // chunk length (8 steps per scan dispatch)
constexpr int kNC = kS / kC;         // 64 chunks
constexpr int kSC  = 8;              // chunks per super-chunk (boundary level 2)
constexpr int kNSC = kNC / kSC;      // 8 super-chunks
#define EPS 1e-5f

typedef __attribute__((ext_vector_type(8))) short short8;
typedef __attribute__((ext_vector_type(4))) float f32x4;

// ---------------- bf16 helpers ----------------
__device__ __forceinline__ ushort f2b(float f){
  unsigned u; __builtin_memcpy(&u, &f, 4);
  unsigned r = (u + 0x7fffu + ((u >> 16) & 1u)) >> 16;  // RNE
  return (ushort)r;
}
__device__ __forceinline__ float b2f(ushort u){
  unsigned v = ((unsigned)u) << 16; float f; __builtin_memcpy(&f, &v, 4); return f;
}
__device__ __forceinline__ void unpack2(unsigned u, float& a, float& b){
  unsigned lo = u << 16, hi = u & 0xffff0000u;
  __builtin_memcpy(&a, &lo, 4); __builtin_memcpy(&b, &hi, 4);
}

// ---------------- prep: fp32 -> bf16 cast with scale ----------------
__global__ void cast_scale(const float* __restrict__ src, ushort* __restrict__ dst,
                           int n, float s){
  int i = blockIdx.x*256 + threadIdx.x;
  if (i < n) dst[i] = f2b(src[i]*s);
}

__global__ void zero_f32(float* __restrict__ p, int n){
  int i = blockIdx.x*256 + threadIdx.x;
  if (i < n) p[i] = 0.f;
}

// Afp[l][m][n] = (m==n ? 0.9 : 0) + float(bf16(0.1*Wh[l][n][m]))  -- row-major fp32
__global__ void prep_afp(const float* __restrict__ Wh, float* __restrict__ Afp){
  int i = blockIdx.x*256 + threadIdx.x;
  if (i >= kL*kH*kH) return;
  const int l = i >> 18, rem = i & 262143;
  const int m = rem >> 9, n = rem & 511;
  float v = b2f(f2b(0.1f * Wh[(size_t)l*kH*kH + (size_t)n*kH + m]));
  if (m == n) v += 0.9f;
  Afp[(size_t)l*kH*kH + (size_t)m*kH + n] = v;
}

// fp32 squaring GEMM, batched over 4 layers: Out[l] = In[l] @ In[l]
__global__ __launch_bounds__(512) void sqgemm(const float* __restrict__ In,
                                              float* __restrict__ Out){
  const int l = blockIdx.x >> 6;       // 4 layers
  const int rg = blockIdx.x & 63;      // row-group of 8
  const int j = threadIdx.x;
  const float* A = In + (size_t)l*kH*kH;
  float* C = Out + (size_t)l*kH*kH;
  __shared__ float ar[8][kH];
  #pragma unroll
  for (int r = 0; r < 8; ++r) ar[r][j] = A[(size_t)(rg*8 + r)*kH + j];
  __syncthreads();
  float acc[8] = {0,0,0,0,0,0,0,0};
  for (int k = 0; k < kH; ++k){
    const float bkj = A[(size_t)k*kH + j];
    #pragma unroll
    for (int r = 0; r < 8; ++r) acc[r] += ar[r][k] * bkj;
  }
  #pragma unroll
  for (int r = 0; r < 8; ++r) C[(size_t)(rg*8 + r)*kH + j] = acc[r];
}

// ---------------- MFMA GEMM, LDS-staged 128x128 tile ----------------
// C[M,N](bf16) = A[M,K](bf16) @ W[N,K]^T + bias.
// 256 threads, 4 waves in 2x2; per K-step-32: reg-stage A/B 128x32 into
// padded LDS (LDT=40 -> 80B rows, 16B-aligned), each wave 16 MFMA from
// 8 ds_read_b128 fragments. Same fragment convention as validated gemm.
__global__ __launch_bounds__(256) void gemm_bf16(
    const ushort* __restrict__ A, const ushort* __restrict__ W,
    ushort* __restrict__ C, int M, int N, int K,
    const float* __restrict__ pb1, const float* __restrict__ pb2, float bscale)
{
  const int NT = N >> 7;
  const int mt = blockIdx.x / NT, ng = blockIdx.x % NT;
  const int tid = threadIdx.x, wave = tid >> 6, lane = tid & 63;
  const int wr = wave >> 1, wc = wave & 1;
  const int r = lane & 15, quad = lane >> 4;

  constexpr int LDT = 40;   // padded row stride in bf16 (80B = 5*16B)
  __shared__ __align__(16) ushort As[128*LDT];
  __shared__ __align__(16) ushort Bs[128*LDT];

  // staging: unit u in [0,512): row=u>>2, c8=u&3; this thread covers u=tid, tid+256
  const int row0 = tid >> 2,        c80 = tid & 3;
  const int row1 = (tid + 256) >> 2, c81 = (tid + 256) & 3;

  f32x4 acc[4][4];
  #pragma unroll
  for (int t = 0; t < 4; ++t)
    #pragma unroll
    for (int j = 0; j < 4; ++j) acc[t][j] = (f32x4){0,0,0,0};

  const ushort* Abase = A + (size_t)(mt*128)*K;
  const ushort* Wbase = W + (size_t)(ng*128)*K;

  for (int k0 = 0; k0 < K; k0 += 32){
    // issue global loads early (latency hides under prior step's compute drain)
    uint4 av0 = *(const uint4*)(Abase + (size_t)row0*K + k0 + c80*8);
    uint4 av1 = *(const uint4*)(Abase + (size_t)row1*K + k0 + c81*8);
    uint4 bv0 = *(const uint4*)(Wbase + (size_t)row0*K + k0 + c80*8);
    uint4 bv1 = *(const uint4*)(Wbase + (size_t)row1*K + k0 + c81*8);
    __syncthreads();   // all waves done reading previous tiles
    *(uint4*)&As[row0*LDT + c80*8] = av0;
    *(uint4*)&As[row1*LDT + c81*8] = av1;
    *(uint4*)&Bs[row0*LDT + c80*8] = bv0;
    *(uint4*)&Bs[row1*LDT + c81*8] = bv1;
    __syncthreads();   // tiles visible

    short8 af[4], bf[4];
    #pragma unroll
    for (int t = 0; t < 4; ++t){
      af[t] = *(const short8*)&As[(wr*64 + t*16 + r)*LDT + quad*8];
      bf[t] = *(const short8*)&Bs[(wc*64 + t*16 + r)*LDT + quad*8];
    }
    #pragma unroll
    for (int t = 0; t < 4; ++t){
      #pragma unroll
      for (int j = 0; j < 4; ++j)
        acc[t][j] = __builtin_amdgcn_mfma_f32_16x16x32_bf16(af[t], bf[j],
                                                            acc[t][j], 0, 0, 0);
    }
  }

  #pragma unroll
  for (int j = 0; j < 4; ++j){
    const int nn = ng*128 + wc*64 + j*16 + r;
    float bias = 0.f;
    if (pb1) bias += pb1[nn];
    if (pb2) bias += pb2[nn];
    bias *= bscale;
    #pragma unroll
    for (int t = 0; t < 4; ++t){
      #pragma unroll
      for (int i = 0; i < 4; ++i){
        const int mm = mt*128 + wr*64 + t*16 + quad*4 + i;
        C[(size_t)mm*N + nn] = f2b(acc[t][j][i] + bias);
      }
    }
  }
}

// ================= chunked scan, MFMA + double-buffered LDS =================
// grid = 256 blocks = 64 chunks x 4 batch-groups of 16 batches; 8 waves/block.
template<bool FULL>
__global__ __launch_bounds__(512) void scan_mfma(
    const ushort* __restrict__ U,     // (B,S,H) bf16
    const ushort* __restrict__ G,     // (H,H) bf16 row-major [n][m] = bf16(0.1*Wh)
    const float* __restrict__ S,      // (B,NC,H) chunk-entry states (FULL only)
    float* __restrict__ Z,            // (B,NC,H) chunk-end states (!FULL only)
    ushort* __restrict__ nh)          // (B,S,H) bf16 (FULL only)
{
  const int c  = blockIdx.x & (kNC - 1);
  const int b0 = (blockIdx.x / kNC) * 16;
  const int wave = threadIdx.x >> 6, lane = threadIdx.x & 63;
  const int r = lane & 15, quad = lane >> 4;
  const int wbase = wave * 64;        // this wave's 64 output columns
  const int colq = quad * 4;          // column sub-offset within a 16-tile

  __shared__ __align__(16) ushort hiL[2][16*kH];
  __shared__ __align__(16) ushort loL[2][16*kH];

  // swizzled byte offset into a [16][512] bf16 tile
  #define SWZ(row, bytecol) ((row)*1024 + ((bytecol) ^ (((row)&7) << 4)))

  const ushort* gp0 = G + (size_t)(wbase +  0 + r)*kH + quad*8;
  const ushort* gp1 = G + (size_t)(wbase + 16 + r)*kH + quad*8;
  const ushort* gp2 = G + (size_t)(wbase + 32 + r)*kH + quad*8;
  const ushort* gp3 = G + (size_t)(wbase + 48 + r)*kH + quad*8;

  float st[4][4];
  #pragma unroll
  for (int t = 0; t < 4; ++t){
    if (FULL){
      const float4 s4 = *(const float4*)&S[((size_t)(b0 + r)*kNC + c)*kH
                                           + wbase + t*16 + colq];
      st[t][0] = s4.x; st[t][1] = s4.y; st[t][2] = s4.z; st[t][3] = s4.w;
    } else {
      st[t][0] = st[t][1] = st[t][2] = st[t][3] = 0.f;
    }
  }

  #pragma unroll
  for (int t = 0; t < 4; ++t){
    ushort h[4], l[4];
    #pragma unroll
    for (int i = 0; i < 4; ++i){
      h[i] = f2b(st[t][i]);
      l[i] = f2b(st[t][i] - b2f(h[i]));
    }
    uint2 hw, lw;
    hw.x = (unsigned)h[0] | ((unsigned)h[1] << 16);
    hw.y = (unsigned)h[2] | ((unsigned)h[3] << 16);
    lw.x = (unsigned)l[0] | ((unsigned)l[1] << 16);
    lw.y = (unsigned)l[2] | ((unsigned)l[3] << 16);
    const int bc = (wbase + t*16 + colq) * 2;
    *(uint2*)((char*)hiL[0] + SWZ(r, bc)) = hw;
    *(uint2*)((char*)loL[0] + SWZ(r, bc)) = lw;
  }
  __syncthreads();

  const size_t ubase = (size_t)(b0 + r)*kS*kH;
  int cur = 0;

  for (int jj = 0; jj < kC; ++jj){
    const int tt = c*kC + jj;

    uint2 uv[4];
    #pragma unroll
    for (int t = 0; t < 4; ++t)
      uv[t] = *(const uint2*)&U[ubase + (size_t)tt*kH + wbase + t*16 + colq];

    const char* rdHi = (const char*)hiL[cur];
    const char* rdLo = (const char*)loL[cur];
    char* wrHi = (char*)hiL[cur ^ 1];
    char* wrLo = (char*)loL[cur ^ 1];

    f32x4 ah0 = {0,0,0,0}, ah1 = {0,0,0,0}, ah2 = {0,0,0,0}, ah3 = {0,0,0,0};
    f32x4 al0 = {0,0,0,0}, al1 = {0,0,0,0}, al2 = {0,0,0,0}, al3 = {0,0,0,0};
    __builtin_amdgcn_s_setprio(1);
    #pragma unroll 4
    for (int k0 = 0; k0 < kH; k0 += 32){
      const int rb = k0*2 + quad*16;   // 16B-aligned, swizzle-safe
      const short8 bh = *(const short8*)(rdHi + SWZ(r, rb));
      const short8 bl = *(const short8*)(rdLo + SWZ(r, rb));
      const short8 g0 = *(const short8*)(gp0 + k0);
      const short8 g1 = *(const short8*)(gp1 + k0);
      const short8 g2 = *(const short8*)(gp2 + k0);
      const short8 g3 = *(const short8*)(gp3 + k0);
      ah0 = __builtin_amdgcn_mfma_f32_16x16x32_bf16(g0, bh, ah0, 0, 0, 0);
      ah1 = __builtin_amdgcn_mfma_f32_16x16x32_bf16(g1, bh, ah1, 0, 0, 0);
      ah2 = __builtin_amdgcn_mfma_f32_16x16x32_bf16(g2, bh, ah2, 0, 0, 0);
      ah3 = __builtin_amdgcn_mfma_f32_16x16x32_bf16(g3, bh, ah3, 0, 0, 0);
      al0 = __builtin_amdgcn_mfma_f32_16x16x32_bf16(g0, bl, al0, 0, 0, 0);
      al1 = __builtin_amdgcn_mfma_f32_16x16x32_bf16(g1, bl, al1, 0, 0, 0);
      al2 = __builtin_amdgcn_mfma_f32_16x16x32_bf16(g2, bl, al2, 0, 0, 0);
      al3 = __builtin_amdgcn_mfma_f32_16x16x32_bf16(g3, bl, al3, 0, 0, 0);
    }
    __builtin_amdgcn_s_setprio(0);
    const f32x4 acs[4] = {ah0 + al0, ah1 + al1, ah2 + al2, ah3 + al3};

    #pragma unroll
    for (int t = 0; t < 4; ++t){
      float u0, u1, u2, u3;
      unpack2(uv[t].x, u0, u1); unpack2(uv[t].y, u2, u3);
      const float n0 = 0.9f*st[t][0] + u0 + acs[t][0];
      const float n1 = 0.9f*st[t][1] + u1 + acs[t][1];
      const float n2 = 0.9f*st[t][2] + u2 + acs[t][2];
      const float n3 = 0.9f*st[t][3] + u3 + acs[t][3];
      st[t][0] = n0; st[t][1] = n1; st[t][2] = n2; st[t][3] = n3;
      const ushort h0 = f2b(n0), h1 = f2b(n1), h2 = f2b(n2), h3 = f2b(n3);
      const ushort l0 = f2b(n0 - b2f(h0)), l1 = f2b(n1 - b2f(h1));
      const ushort l2 = f2b(n2 - b2f(h2)), l3 = f2b(n3 - b2f(h3));
      uint2 hw, lw;
      hw.x = (unsigned)h0 | ((unsigned)h1 << 16);
      hw.y = (unsigned)h2 | ((unsigned)h3 << 16);
      lw.x = (unsigned)l0 | ((unsigned)l1 << 16);
      lw.y = (unsigned)l2 | ((unsigned)l3 << 16);
      const int bc = (wbase + t*16 + colq) * 2;
      *(uint2*)(wrHi + SWZ(r, bc)) = hw;
      *(uint2*)(wrLo + SWZ(r, bc)) = lw;
      if (FULL)
        *(uint2*)&nh[ubase + (size_t)tt*kH + wbase + t*16 + colq] = hw;
    }
    __syncthreads();   // single barrier: writes to cur^1 visible, reads of cur done
    cur ^= 1;
  }

  if (!FULL){
    #pragma unroll
    for (int t = 0; t < 4; ++t){
      float4 z4; z4.x = st[t][0]; z4.y = st[t][1]; z4.z = st[t][2]; z4.w = st[t][3];
      *(float4*)&Z[((size_t)(b0 + r)*kNC + c)*kH + wbase + t*16 + colq] = z4;
    }
  }
  #undef SWZ
}

// ================= two-level boundary scan (fp32, coalesced, float4 s-reads) ==
// (a) P8[b][cc] = zero-init state propagated through chunks cc*kSC .. +kSC-1
__global__ __launch_bounds__(512) void bscan_a(
    const float* __restrict__ A8, const float* __restrict__ Z,
    float* __restrict__ P8)
{
  const int b = blockIdx.x / kNSC, cc = blockIdx.x % kNSC;   // 512 blocks
  const int n = threadIdx.x;
  __shared__ float s[kH];
  s[n] = Z[((size_t)b*kNC + cc*kSC)*kH + n];
  __syncthreads();
  for (int j = 1; j < kSC; ++j){
    float acc = Z[((size_t)b*kNC + cc*kSC + j)*kH + n];
    for (int m = 0; m < kH; m += 4){
      const float4 sv = *(const float4*)&s[m];
      acc += sv.x*A8[(size_t)m*kH + n]     + sv.y*A8[(size_t)(m+1)*kH + n]
           + sv.z*A8[(size_t)(m+2)*kH + n] + sv.w*A8[(size_t)(m+3)*kH + n];
    }
    __syncthreads();
    s[n] = acc;
    __syncthreads();
  }
  P8[((size_t)b*kNSC + cc)*kH + n] = s[n];
}

// (b) S2[b][cc] = state entering super-chunk cc
__global__ __launch_bounds__(512) void bscan_b(
    const float* __restrict__ A64, const float* __restrict__ P8,
    float* __restrict__ S2)
{
  const int b = blockIdx.x, n = threadIdx.x;             // 64 blocks
  __shared__ float s[kH];
  S2[((size_t)b*kNSC + 0)*kH + n] = 0.f;
  s[n] = P8[((size_t)b*kNSC + 0)*kH + n];
  S2[((size_t)b*kNSC + 1)*kH + n] = s[n];
  __syncthreads();
  for (int cc = 1; cc < kNSC - 1; ++cc){
    float acc = P8[((size_t)b*kNSC + cc)*kH + n];
    for (int m = 0; m < kH; m += 4){
      const float4 sv = *(const float4*)&s[m];
      acc += sv.x*A64[(size_t)m*kH + n]     + sv.y*A64[(size_t)(m+1)*kH + n]
           + sv.z*A64[(size_t)(m+2)*kH + n] + sv.w*A64[(size_t)(m+3)*kH + n];
    }
    __syncthreads();
    s[n] = acc;
    S2[((size_t)b*kNSC + cc + 1)*kH + n] = acc;
    __syncthreads();
  }
}

// (c) emit all chunk-entry states within each super-chunk
__global__ __launch_bounds__(512) void bscan_c(
    const float* __restrict__ A8, const float* __restrict__ Z,
    const float* __restrict__ S2, float* __restrict__ S)
{
  const int b = blockIdx.x / kNSC, cc = blockIdx.x % kNSC;   // 512 blocks
  const int n = threadIdx.x;
  __shared__ float s[kH];
  s[n] = S2[((size_t)b*kNSC + cc)*kH + n];
  S[((size_t)b*kNC + cc*kSC)*kH + n] = s[n];
  __syncthreads();
  for (int j = 0; j < kSC - 1; ++j){
    float acc = Z[((size_t)b*kNC + cc*kSC + j)*kH + n];
    for (int m = 0; m < kH; m += 4){
      const float4 sv = *(const float4*)&s[m];
      acc += sv.x*A8[(size_t)m*kH + n]     + sv.y*A8[(size_t)(m+1)*kH + n]
           + sv.z*A8[(size_t)(m+2)*kH + n] + sv.w*A8[(size_t)(m+3)*kH + n];
    }
    __syncthreads();
    s[n] = acc;
    S[((size_t)b*kNC + cc*kSC + j + 1)*kH + n] = acc;
    __syncthreads();
  }
}

// ---------------- LayerNorm rows (in place on bf16) ----------------
__global__ __launch_bounds__(512) void ln_rows(
    ushort* __restrict__ act, const float* __restrict__ g, const float* __restrict__ bta)
{
  const size_t row = blockIdx.x;
  const int n = threadIdx.x, wid = n >> 6, lane = n & 63;
  __shared__ float red[16];
  const float y = b2f(act[row*kH + n]);
  float s1 = y, s2 = y*y;
  #pragma unroll
  for (int off = 32; off; off >>= 1){
    s1 += __shfl_down(s1, off); s2 += __shfl_down(s2, off);
  }
  if (lane == 0){ red[wid] = s1; red[8 + wid] = s2; }
  __syncthreads();
  float m = 0.f, q = 0.f;
  #pragma unroll
  for (int i = 0; i < 8; ++i){ m += red[i]; q += red[8+i]; }
  m *= (1.f/kH); q *= (1.f/kH);
  const float var = q - m*m;
  const float hv = (y - m) * rsqrtf(var + EPS) * g[n] + bta[n];
  act[row*kH + n] = f2b(hv);
}

// ---------------- seqmean (fp32) from bf16 act ----------------
__global__ __launch_bounds__(512) void seqmean_k(
    const ushort* __restrict__ act, float* __restrict__ seqmean)
{
  const int b = blockIdx.x, n = threadIdx.x;
  float acc = 0.f;
  for (int t = 0; t < kS; ++t) acc += b2f(act[((size_t)b*kS + t)*kH + n]);
  seqmean[(size_t)b*kH + n] = acc * (1.f/kS);
}

// ---------------- MFMA flash attention on precomputed qkv (bf16) -------------
__global__ __launch_bounds__(512) void attn_chunk(
    const ushort* __restrict__ qkv,   // (16*S, 3H) bf16
    float* __restrict__ aomean, int b0)
{
  const int bb = blockIdx.x >> 5;          // batch within chunk
  const int h  = (blockIdx.x >> 2) & 7;    // head
  const int qt = blockIdx.x & 3;           // 128-query tile
  const int tid = threadIdx.x, wave = tid >> 6, lane = tid & 63;
  const int r = lane & 15, quad = lane >> 4;

  __shared__ __align__(16) ushort kt[64][72];      // [key][dim]
  __shared__ __align__(16) ushort vt[64][72];      // transposed: [dim][key]
  __shared__ ushort pt[8][16][72];                 // per-wave P [q_local][key]
  __shared__ float aom[kDH];
  if (tid < kDH) aom[tid] = 0.f;

  const int q0 = qt*128 + wave*16;
  short8 qa0, qa1;
  {
    const ushort* qp = qkv + ((size_t)bb*kS + q0 + r)*(3*kH) + h*kDH + quad*8;
    qa0 = *(const short8*)qp;
    qa1 = *(const short8*)(qp + 32);
  }

  f32x4 oc0={0,0,0,0}, oc1={0,0,0,0}, oc2={0,0,0,0}, oc3={0,0,0,0};
  float mRow[4] = {-1e30f,-1e30f,-1e30f,-1e30f};
  float lRow[4] = {0.f,0.f,0.f,0.f};

  const int srow = tid & 63;
  const int sd0  = (tid >> 6) * 8;

  for (int kt0 = 0; kt0 < kS/64; ++kt0){
    {
      const size_t rbase = ((size_t)bb*kS + kt0*64 + srow)*(3*kH) + h*kDH + sd0;
      *(uint4*)&kt[srow][sd0] = *(const uint4*)(qkv + rbase + kH);
      uint4 v4 = *(const uint4*)(qkv + rbase + 2*kH);
      const ushort* vs = (const ushort*)&v4;
      #pragma unroll
      for (int ii = 0; ii < 8; ++ii) vt[sd0 + ii][srow] = vs[ii];
    }
    __syncthreads();

    f32x4 ac0={0,0,0,0}, ac1={0,0,0,0}, ac2={0,0,0,0}, ac3={0,0,0,0};
    #pragma unroll
    for (int k0 = 0; k0 < 2; ++k0){
      const short8 av = k0 ? qa1 : qa0;
      const short8 b0v = *(const short8*)&kt[ 0 + r][k0*32 + quad*8];
      const short8 b1v = *(const short8*)&kt[16 + r][k0*32 + quad*8];
      const short8 b2v = *(const short8*)&kt[32 + r][k0*32 + quad*8];
      const short8 b3v = *(const short8*)&kt[48 + r][k0*32 + quad*8];
      ac0 = __builtin_amdgcn_mfma_f32_16x16x32_bf16(av, b0v, ac0, 0, 0, 0);
      ac1 = __builtin_amdgcn_mfma_f32_16x16x32_bf16(av, b1v, ac1, 0, 0, 0);
      ac2 = __builtin_amdgcn_mfma_f32_16x16x32_bf16(av, b2v, ac2, 0, 0, 0);
      ac3 = __builtin_amdgcn_mfma_f32_16x16x32_bf16(av, b3v, ac3, 0, 0, 0);
    }
    const f32x4 sc0 = ac0 * 0.125f, sc1 = ac1 * 0.125f,
                sc2 = ac2 * 0.125f, sc3 = ac3 * 0.125f;

    float p0[4], p1[4], p2[4], p3[4];
    #pragma unroll
    for (int i = 0; i < 4; ++i){
      float mx = fmaxf(fmaxf(sc0[i], sc1[i]), fmaxf(sc2[i], sc3[i]));
      #pragma unroll
      for (int off = 1; off < 16; off <<= 1) mx = fmaxf(mx, __shfl_xor(mx, off));
      const float nm = fmaxf(mRow[i], mx);
      const float corr = __expf(mRow[i] - nm);
      mRow[i] = nm;
      p0[i] = __expf(sc0[i] - nm); p1[i] = __expf(sc1[i] - nm);
      p2[i] = __expf(sc2[i] - nm); p3[i] = __expf(sc3[i] - nm);
      float rs = p0[i] + p1[i] + p2[i] + p3[i];
      #pragma unroll
      for (int off = 1; off < 16; off <<= 1) rs += __shfl_xor(rs, off);
      lRow[i] = lRow[i]*corr + rs;
      oc0[i] *= corr; oc1[i] *= corr; oc2[i] *= corr; oc3[i] *= corr;
    }

    #pragma unroll
    for (int i = 0; i < 4; ++i){
      pt[wave][quad*4 + i][ 0 + r] = f2b(p0[i]);
      pt[wave][quad*4 + i][16 + r] = f2b(p1[i]);
      pt[wave][quad*4 + i][32 + r] = f2b(p2[i]);
      pt[wave][quad*4 + i][48 + r] = f2b(p3[i]);
    }

    #pragma unroll
    for (int k0 = 0; k0 < 2; ++k0){
      const short8 pa  = *(const short8*)&pt[wave][r][k0*32 + quad*8];
      const short8 v0v = *(const short8*)&vt[ 0 + r][k0*32 + quad*8];
      const short8 v1v = *(const short8*)&vt[16 + r][k0*32 + quad*8];
      const short8 v2v = *(const short8*)&vt[32 + r][k0*32 + quad*8];
      const short8 v3v = *(const short8*)&vt[48 + r][k0*32 + quad*8];
      oc0 = __builtin_amdgcn_mfma_f32_16x16x32_bf16(pa, v0v, oc0, 0, 0, 0);
      oc1 = __builtin_amdgcn_mfma_f32_16x16x32_bf16(pa, v1v, oc1, 0, 0, 0);
      oc2 = __builtin_amdgcn_mfma_f32_16x16x32_bf16(pa, v2v, oc2, 0, 0, 0);
      oc3 = __builtin_amdgcn_mfma_f32_16x16x32_bf16(pa, v3v, oc3, 0, 0, 0);
    }
    __syncthreads();
  }

  float inv[4];
  #pragma unroll
  for (int i = 0; i < 4; ++i) inv[i] = 1.f / lRow[i];
  {
    float v;
    v = oc0[0]*inv[0] + oc0[1]*inv[1] + oc0[2]*inv[2] + oc0[3]*inv[3];
    v += __shfl_xor(v, 16); v += __shfl_xor(v, 32);
    if (quad == 0) atomicAdd(&aom[ 0 + r], v);
    v = oc1[0]*inv[0] + oc1[1]*inv[1] + oc1[2]*inv[2] + oc1[3]*inv[3];
    v += __shfl_xor(v, 16); v += __shfl_xor(v, 32);
    if (quad == 0) atomicAdd(&aom[16 + r], v);
    v = oc2[0]*inv[0] + oc2[1]*inv[1] + oc2[2]*inv[2] + oc2[3]*inv[3];
    v += __shfl_xor(v, 16); v += __shfl_xor(v, 32);
    if (quad == 0) atomicAdd(&aom[32 + r], v);
    v = oc3[0]*inv[0] + oc3[1]*inv[1] + oc3[2]*inv[2] + oc3[3]*inv[3];
    v += __shfl_xor(v, 16); v += __shfl_xor(v, 32);
    if (quad == 0) atomicAdd(&aom[48 + r], v);
  }
  __syncthreads();
  if (tid < kDH)
    atomicAdd(&aomean[(size_t)(b0 + bb)*kH + h*kDH + tid], aom[tid] * (1.f/kS));
}

// ---- pooled = seqmean + aomean@out_w^T + out_b (fp32) ----
__global__ __launch_bounds__(512) void pooled_kernel(
    const float* __restrict__ seqmean, const float* __restrict__ aomean,
    const float* __restrict__ outw, const float* __restrict__ outb,
    float* __restrict__ pooled)
{
  const int b = blockIdx.x, n = threadIdx.x;
  __shared__ float a[kH];
  a[n] = aomean[(size_t)b*kH + n];
  __syncthreads();
  const float* w = outw + (size_t)n*kH;
  float acc = outb[n];
  for (int m = 0; m < kH; ++m) acc += w[m] * a[m];
  pooled[(size_t)b*kH + n] = seqmean[(size_t)b*kH + n] + acc;
}

// ---------------- heads (fp32, validated) ----------------
__global__ __launch_bounds__(256) void heads_kernel(
    const float* __restrict__ pooled,
    const float* Wd1, const float* bd1, const float* Wd2, const float* bd2,
    const float* Wd3, const float* bd3,
    const float* Wq1, const float* bq1, const float* Wq2, const float* bq2,
    const float* Wq3, const float* bq3,
    const float* Wc1, const float* bc1, const float* Wc2, const float* bc2,
    float* __restrict__ out)
{
  const int b = blockIdx.x, tid = threadIdx.x;
  __shared__ float p[kH];
  __shared__ float a1d[256], a1q[256], a1c[256];
  __shared__ float a2d[128], a2q[128];
  p[tid]       = pooled[(size_t)b*kH + tid];
  p[tid + 256] = pooled[(size_t)b*kH + tid + 256];
  __syncthreads();
  {
    const float *w1 = Wd1 + (size_t)tid*kH, *w2 = Wq1 + (size_t)tid*kH,
                *w3 = Wc1 + (size_t)tid*kH;
    float v1 = bd1[tid], v2 = bq1[tid], v3 = bc1[tid];
    for (int m = 0; m < kH; ++m){
      v1 += w1[m]*p[m]; v2 += w2[m]*p[m]; v3 += w3[m]*p[m];
    }
    a1d[tid] = fmaxf(v1, 0.f); a1q[tid] = fmaxf(v2, 0.f); a1c[tid] = fmaxf(v3, 0.f);
  }
  __syncthreads();
  if (tid < 128){
    const float *w1 = Wd2 + (size_t)tid*256, *w2 = Wq2 + (size_t)tid*256;
    float v1 = bd2[tid], v2 = bq2[tid];
    for (int m = 0; m < 256; ++m){ v1 += w1[m]*a1d[m]; v2 += w2[m]*a1q[m]; }
    a2d[tid] = fmaxf(v1, 0.f); a2q[tid] = fmaxf(v2, 0.f);
  }
  __syncthreads();
  if (tid == 0){
    float d0 = bd3[0], d1 = bd3[1], pr = bq3[0], c = bc2[0];
    for (int m = 0; m < 128; ++m){
      d0 += Wd3[m]*a2d[m]; d1 += Wd3[128+m]*a2d[m]; pr += Wq3[m]*a2q[m];
    }
    for (int m = 0; m < 256; ++m) c += Wc2[m]*a1c[m];
    c = 1.f / (1.f + __expf(-c));
    out[2*b + 0]  = d0;
    out[2*b + 1]  = d1;
    out[2*kB + b] = pr;
    out[3*kB + b] = c;
  }
}

// ---------------- launch ----------------
extern "C" void kernel_launch(void* const* d_in, const int* in_sizes, int n_in,
                              void* d_out, int out_size, void* d_ws, size_t ws_size,
                              hipStream_t stream) {
  const float* x    = (const float*)d_in[0];
  const float* Win0 = (const float*)d_in[1];
  const float* bin0 = (const float*)d_in[2];
  const float* Wi   = (const float*)d_in[3];
  const float* bi   = (const float*)d_in[4];
  const float* Wh   = (const float*)d_in[5];
  const float* bh   = (const float*)d_in[6];
  const float* Wo   = (const float*)d_in[7];
  const float* bo   = (const float*)d_in[8];
  const float* lng  = (const float*)d_in[9];
  const float* lnb  = (const float*)d_in[10];
  const float* ipw  = (const float*)d_in[11];
  const float* ipb  = (const float*)d_in[12];
  const float* outw = (const float*)d_in[13];
  const float* outb = (const float*)d_in[14];

  char* wsb = (char*)d_ws;
  const size_t MB = 1u << 20;
  ushort* act   = (ushort*)(wsb);               // 32 MiB
  ushort* U     = (ushort*)(wsb + 32*MB);       // 32 MiB (reused as qkv)
  ushort* nh    = (ushort*)(wsb + 64*MB);       // 32 MiB
  ushort* wh_bf = (ushort*)(wsb + 96*MB);       // 2 MiB (0.1-scaled Wh, [n][m])
  ushort* wi_bf = (ushort*)(wsb + 98*MB);       // 2 MiB (0.1-scaled)
  ushort* wo_bf = (ushort*)(wsb + 100*MB);      // 2 MiB
  float*  Afp   = (float*)(wsb + 102*MB);       // 4 MiB (ends A^64)
  float*  Afp2  = (float*)(wsb + 106*MB);       // 4 MiB (ends A^8)
  // 110-114MB region unused this round
  ushort* w0_bf = (ushort*)(wsb + 114*MB);      // 64 KiB
  ushort* ip_bf = (ushort*)(wsb + 114*MB + 65536);            // 1.5 MiB
  ushort* x_bf  = (ushort*)(wsb + 114*MB + 65536 + 1572864);  // 4 MiB
  float*  Apow  = (float*)x_bf;                 // A^32 temp (after input gemm)
  // act dead-window overlays (between Wi-gemm read and Wo-gemm write):
  float*  Zb    = (float*)act;                  // 8 MiB (B*NC*H fp32, NC=64)
  float*  S     = (float*)(wsb + 8*MB);         // 8 MiB (chunk-entry states)
  float*  P8    = (float*)(wsb + 16*MB);        // 1 MiB
  float*  S2    = (float*)(wsb + 17*MB);        // 1 MiB
  char*   tail  = wsb + 114*MB + 65536 + 1572864 + 4194304;
  float* seqmean = (float*)tail;
  float* aomean  = seqmean + (size_t)kB*kH;
  float* pooled  = aomean  + (size_t)kB*kH;
  ushort* qkv    = U;   // overlay: U dead after scan phase

  // ---- prep casts ----
  cast_scale<<<(kB*kS*kF + 255)/256, 256, 0, stream>>>(x, x_bf, kB*kS*kF, 1.f);
  cast_scale<<<(kH*kF + 255)/256, 256, 0, stream>>>(Win0, w0_bf, kH*kF, 1.f);
  cast_scale<<<(kL*kH*kH + 255)/256, 256, 0, stream>>>(Wi, wi_bf, kL*kH*kH, 0.1f);
  cast_scale<<<(kL*kH*kH + 255)/256, 256, 0, stream>>>(Wo, wo_bf, kL*kH*kH, 1.f);
  cast_scale<<<(kL*kH*kH + 255)/256, 256, 0, stream>>>(Wh, wh_bf, kL*kH*kH, 0.1f);
  cast_scale<<<(3*kH*kH + 255)/256, 256, 0, stream>>>(ipw, ip_bf, 3*kH*kH, 1.f);
  prep_afp<<<(kL*kH*kH + 255)/256, 256, 0, stream>>>(Wh, Afp);
  // A^8 (ends in Afp2)
  sqgemm<<<kL*64, 512, 0, stream>>>(Afp,  Afp2);   // A^2
  sqgemm<<<kL*64, 512, 0, stream>>>(Afp2, Afp);    // A^4
  sqgemm<<<kL*64, 512, 0, stream>>>(Afp,  Afp2);   // A^8  (keep)

  constexpr int M = kB*kS;   // 32768
  // input gemm consumes x_bf BEFORE Apow reuses its region
  gemm_bf16<<<(M/128)*(kH/128), 256, 0, stream>>>(x_bf, w0_bf, act, M, kH, kF,
                                                  bin0, nullptr, 1.f);
  // A^64 (ends in Afp); A^32 temp clobbers x_bf (now dead)
  sqgemm<<<kL*64, 512, 0, stream>>>(Afp2, Afp);    // A^16 (clobbers A^4, dead)
  sqgemm<<<kL*64, 512, 0, stream>>>(Afp,  Apow);   // A^32
  sqgemm<<<kL*64, 512, 0, stream>>>(Apow, Afp);    // A^64 (keep)

  for (int l = 0; l < kL; ++l){
    gemm_bf16<<<(M/128)*(kH/128), 256, 0, stream>>>(
        act, wi_bf + (size_t)l*kH*kH, U, M, kH, kH,
        bi + (size_t)l*kH, bh + (size_t)l*kH, 0.1f);
    scan_mfma<false><<<4*kNC, 512, 0, stream>>>(U, wh_bf + (size_t)l*kH*kH,
                                                nullptr, Zb, nullptr);
    bscan_a<<<kB*kNSC, 512, 0, stream>>>(Afp2 + (size_t)l*kH*kH, Zb, P8);
    bscan_b<<<kB, 512, 0, stream>>>(Afp + (size_t)l*kH*kH, P8, S2);
    bscan_c<<<kB*kNSC, 512, 0, stream>>>(Afp2 + (size_t)l*kH*kH, Zb, S2, S);
    scan_mfma<true><<<4*kNC, 512, 0, stream>>>(U, wh_bf + (size_t)l*kH*kH,
                                               S, nullptr, nh);
    gemm_bf16<<<(M/128)*(kH/128), 256, 0, stream>>>(
        nh, wo_bf + (size_t)l*kH*kH, act, M, kH, kH,
        bo + (size_t)l*kH, nullptr, 1.f);
    ln_rows<<<M, kH, 0, stream>>>(act, lng + (size_t)l*kH, lnb + (size_t)l*kH);
  }

  seqmean_k<<<kB, kH, 0, stream>>>(act, seqmean);

  zero_f32<<<(kB*kH + 255)/256, 256, 0, stream>>>(aomean, kB*kH);
  for (int c = 0; c < 4; ++c){
    const int Mc = 16*kS;   // 8192
    gemm_bf16<<<(Mc/128)*(3*kH/128), 256, 0, stream>>>(
        act + (size_t)c*Mc*kH, ip_bf, qkv, Mc, 3*kH, kH, ipb, nullptr, 1.f);
    attn_chunk<<<512, 512, 0, stream>>>(qkv, aomean, c*16);
  }

  pooled_kernel<<<kB, kH, 0, stream>>>(seqmean, aomean, outw, outb, pooled);

  heads_kernel<<<kB, 256, 0, stream>>>(pooled,
      (const float*)d_in[15], (const float*)d_in[16], (const float*)d_in[17],
      (const float*)d_in[18], (const float*)d_in[19], (const float*)d_in[20],
      (const float*)d_in[21], (const float*)d_in[22], (const float*)d_in[23],
      (const float*)d_in[24], (const float*)d_in[25], (const float*)d_in[26],
      (const float*)d_in[27], (const float*)d_in[28], (const float*)d_in[29],
      (const float*)d_in[30], (float*)d_out);
}